// Round 10
// baseline (422.238 us; speedup 1.0000x reference)
//
#include <hip/hip_runtime.h>
#include <hip/hip_bf16.h>

using bf16x8 = __attribute__((ext_vector_type(8))) short;
using f32x4  = __attribute__((ext_vector_type(4))) float;
using f32x16 = __attribute__((ext_vector_type(16))) float;
typedef unsigned int u32;
typedef unsigned short u16;
using u32x4 = __attribute__((ext_vector_type(4))) u32;

__device__ __forceinline__ u16 f2b(float f) {
  union { float f; u32 u; } v; v.f = f;
  return (u16)((v.u + 0x7FFFu + ((v.u >> 16) & 1u)) >> 16);
}

__device__ __forceinline__ float b2f(u16 b) {
  union { u32 u; float f; } v; v.u = ((u32)b) << 16;
  return v.f;
}

__device__ __forceinline__ u32 cvtpk(float lo, float hi) {
  u32 r;
  asm("v_cvt_pk_bf16_f32 %0, %1, %2" : "=v"(r) : "v"(lo), "v"(hi));
  return r;
}

__device__ __forceinline__ float exp2_raw(float x) {
  float r;
  asm("v_exp_f32 %0, %1" : "=v"(r) : "v"(x));
  return r;
}

__device__ __forceinline__ void gload16(const void* g, void* l) {
  __builtin_amdgcn_global_load_lds((const __attribute__((address_space(1))) u32*)g,
                                   (__attribute__((address_space(3))) u32*)l, 16, 0, 0);
}

// gelu via tanh approx: x * u/(u+1), u = 2^(2*0.79788456*log2e*(x+0.044715x^3))
__device__ __forceinline__ float gelu_fast(float x) {
  const float x2 = x * x;
  const float t = x * fmaf(0.044715f, x2, 1.f);
  const float u = exp2f(2.3022080f * t);
  return x * u * __builtin_amdgcn_rcpf(u + 1.f);
}

// ---------------------------------------------------------------------------
// Fused weight cast fp32 -> bf16 (QKV packed; FF1 a/gate interleaved per 16)
// ---------------------------------------------------------------------------
__global__ __launch_bounds__(256) void castall(
    const float* __restrict__ wq1, const float* __restrict__ wk1,
    const float* __restrict__ wv1, const float* __restrict__ wo1,
    const float* __restrict__ wq2, const float* __restrict__ wk2,
    const float* __restrict__ wv2, const float* __restrict__ wo2,
    const float* __restrict__ wff1, const float* __restrict__ wff2,
    u16* __restrict__ qkv1, u16* __restrict__ o1,
    u16* __restrict__ qkv2, u16* __restrict__ o2,
    u16* __restrict__ ff1p, u16* __restrict__ ff2) {
  const long e = ((long)blockIdx.x * 256 + threadIdx.x) * 4;
  constexpr long M1 = 1l << 20;
  const float* s; u16* d;
  if (e < 3 * M1) {
    s = (e < M1 ? wq1 + e : (e < 2 * M1 ? wk1 + (e - M1) : wv1 + (e - 2 * M1)));
    d = qkv1 + e;
  } else if (e < 4 * M1) {
    s = wo1 + (e - 3 * M1); d = o1 + (e - 3 * M1);
  } else if (e < 7 * M1) {
    long r = e - 4 * M1;
    s = (r < M1 ? wq2 + r : (r < 2 * M1 ? wk2 + (r - M1) : wv2 + (r - 2 * M1)));
    d = qkv2 + r;
  } else if (e < 8 * M1) {
    s = wo2 + (e - 7 * M1); d = o2 + (e - 7 * M1);
  } else if (e < 16 * M1) {
    long r = e - 8 * M1;
    long p = r >> 10, col = r & 1023;
    long g = p >> 5, rr = p & 31;
    long lr = (rr < 16) ? (g << 4) + rr : 4096 + (g << 4) + (rr - 16);
    s = wff1 + (lr << 10) + col; d = ff1p + r;
  } else {
    long r = e - 16 * M1;
    s = wff2 + r; d = ff2 + r;
  }
  float4 v = *(const float4*)s;
  ushort4 o;
  o.x = f2b(v.x); o.y = f2b(v.y); o.z = f2b(v.z); o.w = f2b(v.w);
  *(ushort4*)d = o;
}

// ---------------------------------------------------------------------------
// LayerNorm: one block per row of 1024, fp32 in -> bf16 out
// ---------------------------------------------------------------------------
__global__ __launch_bounds__(256) void ln_kernel(const float* __restrict__ x,
                                                 const float* __restrict__ g,
                                                 const float* __restrict__ b,
                                                 u16* __restrict__ y) {
  const int row = blockIdx.x;
  const int t = threadIdx.x;
  const float* xr = x + (size_t)row * 1024;
  float4 v = ((const float4*)xr)[t];
  float s  = v.x + v.y + v.z + v.w;
  float s2 = v.x * v.x + v.y * v.y + v.z * v.z + v.w * v.w;
  #pragma unroll
  for (int m = 1; m < 64; m <<= 1) {
    s  += __shfl_xor(s, m);
    s2 += __shfl_xor(s2, m);
  }
  __shared__ float red[8];
  if ((t & 63) == 0) { red[(t >> 6) * 2] = s; red[(t >> 6) * 2 + 1] = s2; }
  __syncthreads();
  s  = red[0] + red[2] + red[4] + red[6];
  s2 = red[1] + red[3] + red[5] + red[7];
  const float mu = s * (1.f / 1024.f);
  const float var = s2 * (1.f / 1024.f) - mu * mu;
  const float rs = rsqrtf(var + 1e-5f);
  float4 gv = ((const float4*)g)[t];
  float4 bv = ((const float4*)b)[t];
  ushort4 o;
  o.x = f2b((v.x - mu) * rs * gv.x + bv.x);
  o.y = f2b((v.y - mu) * rs * gv.y + bv.y);
  o.z = f2b((v.z - mu) * rs * gv.z + bv.z);
  o.w = f2b((v.w - mu) * rs * gv.w + bv.w);
  ((ushort4*)(y + (size_t)row * 1024))[t] = o;
}

// ---------------------------------------------------------------------------
// gemm_out: C[M,N] = A[M,K] @ Bw[N,K]^T, fp32 out = acc + bias + resid.
// 128x128 tile, 8 waves, BK=64, dbuf, XOR swizzle, counted vmcnt, setprio.
// ---------------------------------------------------------------------------
__global__ __launch_bounds__(512, 4) void gemm_out(
    const u16* __restrict__ A, const u16* __restrict__ Bw,
    const float* __restrict__ bias, const float* __restrict__ resid,
    float* __restrict__ out, int N, int K) {
  extern __shared__ u16 lds[];
  const int tid = threadIdx.x;
  const int l = tid & 63, wid = tid >> 6;
  const int li = l & 15, lg = l >> 4;
  const int wr = wid >> 2, wc = wid & 3;
  const int nx = N >> 7;
  const int cpx = gridDim.x >> 3;
  const int v = (blockIdx.x & 7) * cpx + (blockIdx.x >> 3);
  const int by = v / nx, bx = v - by * nx;
  const int m0 = by << 7, n0 = bx << 7;

  const int sr = tid >> 3;
  const int sc = ((tid & 7) ^ (sr & 7)) << 3;
  const int dc = (tid & 7) << 3;
  const int sc0 = (lg * 8) ^ ((li & 7) << 3);
  const int sc1 = sc0 ^ 32;

  f32x4 acc[4][2] = {};

  auto stageA = [&](int kb, int t2) {
    #pragma unroll
    for (int s = 0; s < 2; ++s)
      gload16(A + (size_t)(m0 + s * 64 + sr) * K + t2 * 64 + sc,
              lds + kb * 8192 + (s * 64 + sr) * 64 + dc);
  };
  auto stageB = [&](int kb, int t2) {
    #pragma unroll
    for (int s = 0; s < 2; ++s)
      gload16(Bw + (size_t)(n0 + s * 64 + sr) * K + t2 * 64 + sc,
              lds + 16384 + kb * 8192 + (s * 64 + sr) * 64 + dc);
  };

  const int NT = K >> 6;
  stageA(0, 0); stageB(0, 0);
  __builtin_amdgcn_sched_barrier(0);
  stageA(1, 1); stageB(1, 1);
  __builtin_amdgcn_sched_barrier(0);
  asm volatile("s_waitcnt vmcnt(4)" ::: "memory");
  __builtin_amdgcn_s_barrier();
  __builtin_amdgcn_sched_barrier(0);

  for (int t = 0; t < NT; ++t) {
    const int kb = t & 1;
    const u16* Ab = lds + kb * 8192 + (wr * 64 + li) * 64;
    const u16* Bb = lds + 16384 + kb * 8192 + (wc * 32 + li) * 64;
    bf16x8 a[4], b[2];

    #pragma unroll
    for (int mi = 0; mi < 4; ++mi) a[mi] = *(const bf16x8*)(Ab + mi * 1024 + sc0);
    #pragma unroll
    for (int n = 0; n < 2; ++n)  b[n]  = *(const bf16x8*)(Bb + n * 1024 + sc0);
    __builtin_amdgcn_s_barrier();
    __builtin_amdgcn_s_setprio(1);
    #pragma unroll
    for (int mi = 0; mi < 4; ++mi)
      #pragma unroll
      for (int n = 0; n < 2; ++n)
        acc[mi][n] = __builtin_amdgcn_mfma_f32_16x16x32_bf16(a[mi], b[n], acc[mi][n], 0, 0, 0);
    __builtin_amdgcn_s_setprio(0);
    __builtin_amdgcn_s_barrier();

    #pragma unroll
    for (int mi = 0; mi < 4; ++mi) a[mi] = *(const bf16x8*)(Ab + mi * 1024 + sc1);
    #pragma unroll
    for (int n = 0; n < 2; ++n)  b[n]  = *(const bf16x8*)(Bb + n * 1024 + sc1);
    __builtin_amdgcn_s_barrier();
    __builtin_amdgcn_s_setprio(1);
    #pragma unroll
    for (int mi = 0; mi < 4; ++mi)
      #pragma unroll
      for (int n = 0; n < 2; ++n)
        acc[mi][n] = __builtin_amdgcn_mfma_f32_16x16x32_bf16(a[mi], b[n], acc[mi][n], 0, 0, 0);
    __builtin_amdgcn_s_setprio(0);
    if (t + 2 < NT) {
      stageA(kb, t + 2); stageB(kb, t + 2);
      asm volatile("s_waitcnt vmcnt(4)" ::: "memory");
    } else if (t + 2 == NT) {
      asm volatile("s_waitcnt vmcnt(0)" ::: "memory");
    }
    __builtin_amdgcn_s_barrier();
    __builtin_amdgcn_sched_barrier(0);
  }

  #pragma unroll
  for (int mi = 0; mi < 4; ++mi) {
    const int m = m0 + wr * 64 + mi * 16 + lg * 4;
    #pragma unroll
    for (int n = 0; n < 2; ++n) {
      const int j = n0 + wc * 32 + n * 16 + li;
      const float bj = bias[j];
      #pragma unroll
      for (int rb = 0; rb < 4; ++rb)
        out[(size_t)(m + rb) * N + j] =
            acc[mi][n][rb] + bj + resid[(size_t)(m + rb) * N + j];
    }
  }
}

// ===========================================================================
// 256x256 4-phase K-loop, ONE barrier per phase (4/tile).
// ===========================================================================
#define KLOOP_PROLOGUE()                                                      \
  stageA(0, 0); stageB(0, 0); stageA(1, 0); stageB(1, 0);                     \
  __builtin_amdgcn_sched_barrier(0);                                          \
  stageA(0, 1); stageB(0, 1);                                                 \
  __builtin_amdgcn_sched_barrier(0);                                          \
  asm volatile("s_waitcnt vmcnt(4)" ::: "memory");                            \
  __builtin_amdgcn_s_barrier();                                               \
  __builtin_amdgcn_sched_barrier(0);

#define KLOOP_BODY(NT)                                                        \
  bf16x8 b0[4], b1[4];                                                        \
  for (int t = 0; t < NT; ++t) {                                              \
    const int kb = t & 1;                                                     \
    const u16* Abase0 = lds + (kb * 2 + 0) * 8192 + rowA0;                    \
    const u16* Abase1 = lds + (kb * 2 + 1) * 8192 + rowA0;                    \
    const u16* Bbase  = lds + (kb * 2 + bhn) * 8192 + rowB0;                  \
    bf16x8 a[4];                                                              \
    /* phase 1: (qm0, k0) */                                                  \
    _Pragma("unroll")                                                         \
    for (int j = 0; j < 4; ++j) a[j]  = *(const bf16x8*)(Abase0 + j * 1024 + sc0); \
    _Pragma("unroll")                                                         \
    for (int n = 0; n < 4; ++n) b0[n] = *(const bf16x8*)(Bbase + n * 1024 + sc0); \
    if (t + 1 < NT) stageA(1, t + 1);                                         \
    __builtin_amdgcn_s_setprio(1);                                            \
    _Pragma("unroll")                                                         \
    for (int j = 0; j < 4; ++j)                                               \
      _Pragma("unroll")                                                       \
      for (int n = 0; n < 4; ++n)                                             \
        acc[j][n] = __builtin_amdgcn_mfma_f32_16x16x32_bf16(a[j], b0[n], acc[j][n], 0, 0, 0); \
    __builtin_amdgcn_s_setprio(0);                                            \
    __builtin_amdgcn_s_barrier();                                             \
    /* phase 2: (qm0, k1) */                                                  \
    _Pragma("unroll")                                                         \
    for (int j = 0; j < 4; ++j) a[j]  = *(const bf16x8*)(Abase0 + j * 1024 + sc1); \
    _Pragma("unroll")                                                         \
    for (int n = 0; n < 4; ++n) b1[n] = *(const bf16x8*)(Bbase + n * 1024 + sc1); \
    if (t + 1 < NT) stageB(1, t + 1);                                         \
    __builtin_amdgcn_s_setprio(1);                                            \
    _Pragma("unroll")                                                         \
    for (int j = 0; j < 4; ++j)                                               \
      _Pragma("unroll")                                                       \
      for (int n = 0; n < 4; ++n)                                             \
        acc[j][n] = __builtin_amdgcn_mfma_f32_16x16x32_bf16(a[j], b1[n], acc[j][n], 0, 0, 0); \
    __builtin_amdgcn_s_setprio(0);                                            \
    __builtin_amdgcn_s_barrier();                                             \
    /* phase 3: (qm1, k0) */                                                  \
    _Pragma("unroll")                                                         \
    for (int j = 0; j < 4; ++j) a[j] = *(const bf16x8*)(Abase1 + j * 1024 + sc0); \
    if (t + 2 < NT) stageA(0, t + 2);                                         \
    __builtin_amdgcn_s_setprio(1);                                            \
    _Pragma("unroll")                                                         \
    for (int j = 0; j < 4; ++j)                                               \
      _Pragma("unroll")                                                       \
      for (int n = 0; n < 4; ++n)                                             \
        acc[4 + j][n] = __builtin_amdgcn_mfma_f32_16x16x32_bf16(a[j], b0[n], acc[4 + j][n], 0, 0, 0); \
    __builtin_amdgcn_s_setprio(0);                                            \
    __builtin_amdgcn_s_barrier();                                             \
    /* phase 4: (qm1, k1) */                                                  \
    _Pragma("unroll")                                                         \
    for (int j = 0; j < 4; ++j) a[j] = *(const bf16x8*)(Abase1 + j * 1024 + sc1); \
    if (t + 2 < NT) stageB(0, t + 2);                                         \
    __builtin_amdgcn_s_setprio(1);                                            \
    _Pragma("unroll")                                                         \
    for (int j = 0; j < 4; ++j)                                               \
      _Pragma("unroll")                                                       \
      for (int n = 0; n < 4; ++n)                                             \
        acc[4 + j][n] = __builtin_amdgcn_mfma_f32_16x16x32_bf16(a[j], b1[n], acc[4 + j][n], 0, 0, 0); \
    __builtin_amdgcn_s_setprio(0);                                            \
    if (t < NT - 2)       asm volatile("s_waitcnt vmcnt(4)" ::: "memory");    \
    else if (t == NT - 2) asm volatile("s_waitcnt vmcnt(0)" ::: "memory");    \
    __builtin_amdgcn_s_barrier();                                             \
  }

// ---------------------------------------------------------------------------
// FF1: 256x256 packed-GEGLU GEMM. XCD decode: 8x8 2D chunk per XCD.
// ---------------------------------------------------------------------------
__global__ __launch_bounds__(512, 2) void gemm_ff1(
    const u16* __restrict__ A, const u16* __restrict__ Wp,
    const float* __restrict__ bias, u16* __restrict__ out) {
  extern __shared__ u16 lds[];
  const int tid = threadIdx.x;
  const int l = tid & 63, wid = tid >> 6;
  const int li = l & 15, lg = l >> 4;
  const int wr = wid >> 2, wc = wid & 3;
  const int xcd = blockIdx.x & 7, r = blockIdx.x >> 3;   // r in [0,64)
  const int bx = (xcd & 3) * 8 + (r >> 3);               // [0,32)
  const int by = (xcd >> 2) * 8 + (r & 7);               // [0,16)

  const int lr8 = l >> 3;
  const int scb = ((l & 7) ^ lr8) << 3;
  const int sc0 = (lg * 8) ^ ((li & 7) << 3);
  const int sc1 = sc0 ^ 32;

  const int rowA0 = (wr * 64 + li) * 64;
  const int rowB0 = 32768 + ((wc & 1) * 64 + li) * 64;
  const int bhn = wc >> 1;

  f32x4 acc[8][4] = {};

  auto stageA = [&](int h, int t2) {
    const int kb2 = t2 & 1;
    #pragma unroll
    for (int s = 0; s < 2; ++s) {
      const u16* g = A + (size_t)(by * 256 + s * 128 + h * 64 + wid * 8 + lr8) * 1024
                       + t2 * 64 + scb;
      u16* d = lds + (kb2 * 2 + h) * 8192 + s * 4096 + wid * 512;
      gload16(g, d);
    }
  };
  auto stageB = [&](int h, int t2) {
    const int kb2 = t2 & 1;
    #pragma unroll
    for (int s = 0; s < 2; ++s) {
      const u16* g = Wp + (size_t)(bx * 256 + h * 128 + s * 64 + wid * 8 + lr8) * 1024
                        + t2 * 64 + scb;
      u16* d = lds + 32768 + (kb2 * 2 + h) * 8192 + s * 4096 + wid * 512;
      gload16(g, d);
    }
  };

  KLOOP_PROLOGUE()
  KLOOP_BODY(16)

  #pragma unroll
  for (int nj = 0; nj < 2; ++nj) {
    const int c = bx * 128 + wc * 32 + nj * 16 + li;
    const float ba = bias[c];
    const float bg = bias[4096 + c];
    #pragma unroll
    for (int mi = 0; mi < 8; ++mi) {
      #pragma unroll
      for (int rb = 0; rb < 4; ++rb) {
        const float av = acc[mi][2 * nj][rb] + ba;
        const float gv = acc[mi][2 * nj + 1][rb] + bg;
        out[(size_t)(by * 256 + wr * 128 + mi * 16 + lg * 4 + rb) * 4096 + c]
            = f2b(av * gelu_fast(gv));
      }
    }
  }
}

// ---------------------------------------------------------------------------
// QKV: 256x256 4-phase GEMM, N=3072. XCD decode: 4by x 6bx chunk per XCD.
// ---------------------------------------------------------------------------
__global__ __launch_bounds__(512, 2) void gemm_qkv(
    const u16* __restrict__ A, const u16* __restrict__ Wp,
    u16* __restrict__ outp) {
  extern __shared__ u16 lds[];
  const int tid = threadIdx.x;
  const int l = tid & 63, wid = tid >> 6;
  const int li = l & 15, lg = l >> 4;
  const int wr = wid >> 2, wc = wid & 3;
  const int xcd = blockIdx.x & 7, r = blockIdx.x >> 3;   // r in [0,24)
  const int by = (xcd >> 1) * 4 + r / 6;                 // [0,16)
  const int bx = (xcd & 1) * 6 + r % 6;                  // [0,12)

  const int lr8 = l >> 3;
  const int scb = ((l & 7) ^ lr8) << 3;
  const int sc0 = (lg * 8) ^ ((li & 7) << 3);
  const int sc1 = sc0 ^ 32;

  const int rowA0 = (wr * 64 + li) * 64;
  const int rowB0 = 32768 + ((wc & 1) * 64 + li) * 64;
  const int bhn = wc >> 1;

  f32x4 acc[8][4] = {};

  auto stageA = [&](int h, int t2) {
    const int kb2 = t2 & 1;
    #pragma unroll
    for (int s = 0; s < 2; ++s) {
      const u16* g = A + (size_t)(by * 256 + s * 128 + h * 64 + wid * 8 + lr8) * 1024
                       + t2 * 64 + scb;
      u16* d = lds + (kb2 * 2 + h) * 8192 + s * 4096 + wid * 512;
      gload16(g, d);
    }
  };
  auto stageB = [&](int h, int t2) {
    const int kb2 = t2 & 1;
    #pragma unroll
    for (int s = 0; s < 2; ++s) {
      const u16* g = Wp + (size_t)(bx * 256 + h * 128 + s * 64 + wid * 8 + lr8) * 1024
                        + t2 * 64 + scb;
      u16* d = lds + 32768 + (kb2 * 2 + h) * 8192 + s * 4096 + wid * 512;
      gload16(g, d);
    }
  };

  KLOOP_PROLOGUE()
  KLOOP_BODY(16)

  #pragma unroll
  for (int mi = 0; mi < 8; ++mi) {
    const int mbase = by * 256 + wr * 128 + mi * 16 + lg * 4;
    #pragma unroll
    for (int ni = 0; ni < 4; ++ni) {
      const int j = bx * 256 + wc * 64 + ni * 16 + li;
      f32x4 a = acc[mi][ni];
      const int sec = j >> 10, jj = j & 1023;
      const int h = jj >> 6, dd = jj & 63;
      u16* base = outp + (size_t)sec * 4194304;
      if (sec == 0) {
        #pragma unroll
        for (int rb = 0; rb < 4; ++rb) {
          const int m = mbase + rb;
          const int bb = m >> 11, n = m & 2047;
          base[(((size_t)bb * 16 + h) * 2048 + n) * 64 + dd] =
              f2b(a[rb] * 0.18033688011112042f);
        }
      } else if (sec == 1) {
        #pragma unroll
        for (int rb = 0; rb < 4; ++rb) {
          const int m = mbase + rb;
          const int bb = m >> 11, n = m & 2047;
          base[(((size_t)bb * 16 + h) * 2048 + n) * 64 + (dd ^ ((n & 7) << 3))] =
              f2b(a[rb]);
        }
      } else {
        const int bb = mbase >> 11, n = mbase & 2047;
        const int ng = n & ~63, nl = n & 63;
        const int nl2 = (nl & 51) | ((nl & 4) << 1) | ((nl & 8) >> 1);
        const int col = ng | (nl2 ^ ((dd & 7) << 3));
        ushort4 pk;
        pk.x = f2b(a[0]); pk.y = f2b(a[1]); pk.z = f2b(a[2]); pk.w = f2b(a[3]);
        *(ushort4*)&base[(((size_t)bb * 16 + h) * 64 + dd) * 2048 + col] = pk;
      }
    }
  }
}

// ---------------------------------------------------------------------------
// Split-KV flash attention (static-shift softmax => partials compose by ADD).
// Grid 1024: bh (32) x qt (16, 128 q each) x kh (2 KV halves of 16 tiles).
// 2-buffer LDS (32 KB), vmcnt(0)/tile (R5-proven), 4 blocks/CU occupancy.
// Writes unnormalized bf16 partial O [kh][bh*2048+q][64] + per-row l.
// ---------------------------------------------------------------------------
__global__ __launch_bounds__(256, 4) void attn_split(
    const u16* __restrict__ Q, const u16* __restrict__ K,
    const u16* __restrict__ Vt, u16* __restrict__ Op, float* __restrict__ Lp) {
  __shared__ u16 smem[2][8192];
  const int tid = threadIdx.x;
  const int l = tid & 63, w = tid >> 6;
  const int lo = l & 31, hi = l >> 5, l7 = l & 7;
  const int bh = blockIdx.x & 31;
  const int qt = (blockIdx.x >> 5) & 15;
  const int kh = blockIdx.x >> 9;

  const u16* Qg = Q + ((size_t)bh * 2048 + qt * 128 + w * 32 + lo) * 64;
  const u16* Kg = K + (size_t)bh * 2048 * 64;
  const u16* Vg = Vt + (size_t)bh * 64 * 2048;

  bf16x8 qf[4];
  #pragma unroll
  for (int d = 0; d < 4; ++d) qf[d] = *(const bf16x8*)&Qg[d * 16 + hi * 8];

  f32x16 o0 = {}, o1 = {};
  float lrow = 0.f;

  auto stage = [&](int buf, int jt) {
    #pragma unroll
    for (int i = 0; i < 2; ++i)
      gload16(Kg + (size_t)jt * 4096 + i * 2048 + tid * 8,
              &smem[buf][i * 2048 + w * 512]);
    #pragma unroll
    for (int i = 0; i < 2; ++i)
      gload16(Vg + (size_t)(w * 8 + (l >> 3) + i * 32) * 2048 + jt * 64 + l7 * 8,
              &smem[buf][4096 + i * 2048 + w * 512]);
  };

  stage(0, kh * 16);

  for (int i = 0; i < 16; ++i) {
    const int cur = i & 1;
    asm volatile("s_waitcnt vmcnt(0)" ::: "memory");
    __builtin_amdgcn_s_barrier();
    __builtin_amdgcn_sched_barrier(0);
    if (i + 1 < 16) stage(cur ^ 1, kh * 16 + i + 1);

    const u16* Kl = &smem[cur][0];
    const u16* Vl = &smem[cur][4096];

    bf16x8 kf[4][2], vf0[4], vf1[4];
    #pragma unroll
    for (int dc = 0; dc < 4; ++dc) {
      const int col = (dc * 16 + hi * 8) ^ (l7 << 3);
      kf[dc][0] = *(const bf16x8*)&Kl[lo * 64 + col];
      kf[dc][1] = *(const bf16x8*)&Kl[(32 + lo) * 64 + col];
      vf0[dc]   = *(const bf16x8*)&Vl[lo * 64 + col];
      vf1[dc]   = *(const bf16x8*)&Vl[(32 + lo) * 64 + col];
    }

    f32x16 st[2] = {};
    __builtin_amdgcn_s_setprio(1);
    #pragma unroll
    for (int dc = 0; dc < 4; ++dc) {
      st[0] = __builtin_amdgcn_mfma_f32_32x32x16_bf16(kf[dc][0], qf[dc], st[0], 0, 0, 0);
      st[1] = __builtin_amdgcn_mfma_f32_32x32x16_bf16(kf[dc][1], qf[dc], st[1], 0, 0, 0);
    }
    __builtin_amdgcn_s_setprio(0);

    // P = 2^(st - 8): no max tracking (logits bounded)
    float p[32], sm[16];
    #pragma unroll
    for (int r = 0; r < 16; ++r) p[r]      = exp2_raw(st[0][r] - 8.f);
    #pragma unroll
    for (int r = 0; r < 16; ++r) p[16 + r] = exp2_raw(st[1][r] - 8.f);
    #pragma unroll
    for (int r = 0; r < 16; ++r) sm[r] = p[r] + p[16 + r];
    #pragma unroll
    for (int s2 = 8; s2 >= 1; s2 >>= 1)
      #pragma unroll
      for (int r = 0; r < s2; ++r) sm[r] += sm[r + s2];
    lrow += sm[0] + __shfl_xor(sm[0], 32);

    bf16x8 pf[4];
    #pragma unroll
    for (int kp = 0; kp < 4; ++kp) {
      u32x4 wv;
      #pragma unroll
      for (int t2 = 0; t2 < 4; ++t2)
        wv[t2] = cvtpk(p[(kp >> 1) * 16 + (kp & 1) * 8 + t2 * 2],
                       p[(kp >> 1) * 16 + (kp & 1) * 8 + t2 * 2 + 1]);
      union { u32x4 a; bf16x8 b; } cc; cc.a = wv;
      pf[kp] = cc.b;
    }

    __builtin_amdgcn_s_setprio(1);
    #pragma unroll
    for (int kp = 0; kp < 4; ++kp) {
      o0 = __builtin_amdgcn_mfma_f32_32x32x16_bf16(vf0[kp], pf[kp], o0, 0, 0, 0);
      o1 = __builtin_amdgcn_mfma_f32_32x32x16_bf16(vf1[kp], pf[kp], o1, 0, 0, 0);
    }
    __builtin_amdgcn_s_setprio(0);
    __builtin_amdgcn_s_barrier();
  }

  // partial store (unnormalized, bf16) + l
  const int row = bh * 2048 + qt * 128 + w * 32 + lo;
  u16* Ob = Op + (size_t)kh * 4194304 + (size_t)row * 64;
  #pragma unroll
  for (int dd = 0; dd < 2; ++dd) {
    #pragma unroll
    for (int R = 0; R < 4; ++R) {
      ushort4 pk;
      const f32x16 oo = dd ? o1 : o0;
      pk.x = f2b(oo[4 * R + 0]); pk.y = f2b(oo[4 * R + 1]);
      pk.z = f2b(oo[4 * R + 2]); pk.w = f2b(oo[4 * R + 3]);
      *(ushort4*)&Ob[dd * 32 + 8 * R + 4 * hi] = pk;
    }
  }
  if (hi == 0) Lp[kh * 65536 + row] = lrow;
}

// ---------------------------------------------------------------------------
// Combine: out = (O0+O1)/(l0+l1), write bf16 xn [B,N,1024].
// ---------------------------------------------------------------------------
__global__ __launch_bounds__(256) void attn_combine(
    const u16* __restrict__ Op, const float* __restrict__ Lp,
    u16* __restrict__ xn) {
  const int idx = blockIdx.x * 256 + threadIdx.x;   // 0..524287
  const int row = idx >> 3;                          // 0..65535
  const int dq  = (idx & 7) * 8;
  const int bh = row >> 11, n = row & 2047;
  const int b_ = bh >> 4, h = bh & 15;
  const float inv = 1.f / (Lp[row] + Lp[65536 + row]);
  const size_t oa = (size_t)row * 64 + dq;
  bf16x8 a = *(const bf16x8*)&Op[oa];
  bf16x8 b = *(const bf16x8*)&Op[4194304 + oa];
  union { bf16x8 v; u16 e[8]; } ua, ub, uo;
  ua.v = a; ub.v = b;
  #pragma unroll
  for (int j = 0; j < 8; ++j)
    uo.e[j] = f2b((b2f(ua.e[j]) + b2f(ub.e[j])) * inv);
  *(bf16x8*)&xn[((size_t)b_ * 2048 + n) * 1024 + h * 64 + dq] = uo.v;
}

// ---------------------------------------------------------------------------
// Host launch
// ---------------------------------------------------------------------------
extern "C" void kernel_launch(void* const* d_in, const int* in_sizes, int n_in,
                              void* d_out, int out_size, void* d_ws, size_t ws_size,
                              hipStream_t stream) {
  const float* x    = (const float*)d_in[0];
  const float* ln1g = (const float*)d_in[1];
  const float* ln1b = (const float*)d_in[2];
  const float* wq1  = (const float*)d_in[3];
  const float* wk1  = (const float*)d_in[4];
  const float* wv1  = (const float*)d_in[5];
  const float* wo1  = (const float*)d_in[6];
  const float* bo1  = (const float*)d_in[7];
  const float* ln2g = (const float*)d_in[8];
  const float* ln2b = (const float*)d_in[9];
  const float* wq2  = (const float*)d_in[10];
  const float* wk2  = (const float*)d_in[11];
  const float* wv2  = (const float*)d_in[12];
  const float* wo2  = (const float*)d_in[13];
  const float* bo2  = (const float*)d_in[14];
  const float* ln3g = (const float*)d_in[15];
  const float* ln3b = (const float*)d_in[16];
  const float* wff1 = (const float*)d_in[17];
  const float* bff1 = (const float*)d_in[18];
  const float* wff2 = (const float*)d_in[19];
  const float* bff2 = (const float*)d_in[20];

  char* ws = (char*)d_ws;
  const size_t MB = 1024 * 1024;
  u16* wqkv1b = (u16*)(ws + 0 * MB);
  u16* wo1b   = (u16*)(ws + 6 * MB);
  u16* wqkv2b = (u16*)(ws + 8 * MB);
  u16* wo2b   = (u16*)(ws + 14 * MB);
  u16* wff1p  = (u16*)(ws + 16 * MB);
  u16* wff2b  = (u16*)(ws + 32 * MB);
  u16* xn     = (u16*)(ws + 40 * MB);
  u16* Qb     = (u16*)(ws + 48 * MB);
  float* x1   = (float*)(ws + 72 * MB);
  float* x2   = (float*)(ws + 88 * MB);
  u16* hact   = (u16*)(ws + 48 * MB);
  u16* Kb  = Qb + 4194304;
  u16* Vtb = Qb + 8388608;

  // attn partials live in regions that are dead during each attn phase:
  //   attn1: Opart in x1 region (72-88 MB, written by gemm_out1 AFTER combine1),
  //          Lpart at x2 start (88 MB; x2 written much later).
  //   attn2: Opart in x2 region (88-104 MB, written by gemm_out2 AFTER combine2),
  //          Lpart at 0 MB (wqkv1b, dead after gemm_qkv1; rewritten by castall
  //          at each replay start -> deterministic).
  u16*   Opart1 = (u16*)(ws + 72 * MB);
  float* Lpart1 = (float*)(ws + 88 * MB);
  u16*   Opart2 = (u16*)(ws + 88 * MB);
  float* Lpart2 = (float*)(ws + 0 * MB);

  hipFuncSetAttribute((const void*)gemm_ff1,
                      hipFuncAttributeMaxDynamicSharedMemorySize, 131072);
  hipFuncSetAttribute((const void*)gemm_qkv,
                      hipFuncAttributeMaxDynamicSharedMemorySize, 131072);
  hipFuncSetAttribute((const void*)gemm_out,
                      hipFuncAttributeMaxDynamicSharedMemorySize, 65536);

  castall<<<20480, 256, 0, stream>>>(wq1, wk1, wv1, wo1, wq2, wk2, wv2, wo2,
                                     wff1, wff2,
                                     wqkv1b, wo1b, wqkv2b, wo2b, wff1p, wff2b);

  // ---- attention block 1 ----
  ln_kernel<<<4096, 256, 0, stream>>>(x, ln1g, ln1b, xn);
  gemm_qkv<<<192, 512, 131072, stream>>>(xn, wqkv1b, Qb);
  attn_split<<<1024, 256, 0, stream>>>(Qb, Kb, Vtb, Opart1, Lpart1);
  attn_combine<<<2048, 256, 0, stream>>>(Opart1, Lpart1, xn);
  gemm_out<<<256, 512, 65536, stream>>>(xn, wo1b, bo1, x, x1, 1024, 1024);

  // ---- attention block 2 ----
  ln_kernel<<<4096, 256, 0, stream>>>(x1, ln2g, ln2b, xn);
  gemm_qkv<<<192, 512, 131072, stream>>>(xn, wqkv2b, Qb);
  attn_split<<<1024, 256, 0, stream>>>(Qb, Kb, Vtb, Opart2, Lpart2);
  attn_combine<<<2048, 256, 0, stream>>>(Opart2, Lpart2, xn);
  gemm_out<<<256, 512, 65536, stream>>>(xn, wo2b, bo2, x1, x2, 1024, 1024);

  // ---- GEGLU FF ----
  ln_kernel<<<4096, 256, 0, stream>>>(x2, ln3g, ln3b, xn);
  gemm_ff1<<<512, 512, 131072, stream>>>(xn, wff1p, bff1, hact);
  gemm_out<<<256, 512, 65536, stream>>>(hact, wff2b, bff2, x2, (float*)d_out, 1024, 4096);
}

// Round 11
// 364.041 us; speedup vs baseline: 1.1599x; 1.1599x over previous
//
#include <hip/hip_runtime.h>
#include <hip/hip_bf16.h>

using bf16x8 = __attribute__((ext_vector_type(8))) short;
using f32x4  = __attribute__((ext_vector_type(4))) float;
using f32x16 = __attribute__((ext_vector_type(16))) float;
typedef unsigned int u32;
typedef unsigned short u16;
using u32x4 = __attribute__((ext_vector_type(4))) u32;

__device__ __forceinline__ u16 f2b(float f) {
  union { float f; u32 u; } v; v.f = f;
  return (u16)((v.u + 0x7FFFu + ((v.u >> 16) & 1u)) >> 16);
}

__device__ __forceinline__ u32 cvtpk(float lo, float hi) {
  u32 r;
  asm("v_cvt_pk_bf16_f32 %0, %1, %2" : "=v"(r) : "v"(lo), "v"(hi));
  return r;
}

__device__ __forceinline__ float exp2_raw(float x) {
  float r;
  asm("v_exp_f32 %0, %1" : "=v"(r) : "v"(x));
  return r;
}

__device__ __forceinline__ void gload16(const void* g, void* l) {
  __builtin_amdgcn_global_load_lds((const __attribute__((address_space(1))) u32*)g,
                                   (__attribute__((address_space(3))) u32*)l, 16, 0, 0);
}

// gelu via tanh approx: x * u/(u+1), u = 2^(2*0.79788456*log2e*(x+0.044715x^3))
__device__ __forceinline__ float gelu_fast(float x) {
  const float x2 = x * x;
  const float t = x * fmaf(0.044715f, x2, 1.f);
  const float u = exp2f(2.3022080f * t);
  return x * u * __builtin_amdgcn_rcpf(u + 1.f);
}

// ---------------------------------------------------------------------------
// Fused weight cast fp32 -> bf16 (QKV packed; FF1 a/gate interleaved per 16)
// ---------------------------------------------------------------------------
__global__ __launch_bounds__(256) void castall(
    const float* __restrict__ wq1, const float* __restrict__ wk1,
    const float* __restrict__ wv1, const float* __restrict__ wo1,
    const float* __restrict__ wq2, const float* __restrict__ wk2,
    const float* __restrict__ wv2, const float* __restrict__ wo2,
    const float* __restrict__ wff1, const float* __restrict__ wff2,
    u16* __restrict__ qkv1, u16* __restrict__ o1,
    u16* __restrict__ qkv2, u16* __restrict__ o2,
    u16* __restrict__ ff1p, u16* __restrict__ ff2) {
  const long e = ((long)blockIdx.x * 256 + threadIdx.x) * 4;
  constexpr long M1 = 1l << 20;
  const float* s; u16* d;
  if (e < 3 * M1) {
    s = (e < M1 ? wq1 + e : (e < 2 * M1 ? wk1 + (e - M1) : wv1 + (e - 2 * M1)));
    d = qkv1 + e;
  } else if (e < 4 * M1) {
    s = wo1 + (e - 3 * M1); d = o1 + (e - 3 * M1);
  } else if (e < 7 * M1) {
    long r = e - 4 * M1;
    s = (r < M1 ? wq2 + r : (r < 2 * M1 ? wk2 + (r - M1) : wv2 + (r - 2 * M1)));
    d = qkv2 + r;
  } else if (e < 8 * M1) {
    s = wo2 + (e - 7 * M1); d = o2 + (e - 7 * M1);
  } else if (e < 16 * M1) {
    long r = e - 8 * M1;
    long p = r >> 10, col = r & 1023;
    long g = p >> 5, rr = p & 31;
    long lr = (rr < 16) ? (g << 4) + rr : 4096 + (g << 4) + (rr - 16);
    s = wff1 + (lr << 10) + col; d = ff1p + r;
  } else {
    long r = e - 16 * M1;
    s = wff2 + r; d = ff2 + r;
  }
  float4 v = *(const float4*)s;
  ushort4 o;
  o.x = f2b(v.x); o.y = f2b(v.y); o.z = f2b(v.z); o.w = f2b(v.w);
  *(ushort4*)d = o;
}

// ---------------------------------------------------------------------------
// LayerNorm: one block per row of 1024, fp32 in -> bf16 out
// ---------------------------------------------------------------------------
__global__ __launch_bounds__(256) void ln_kernel(const float* __restrict__ x,
                                                 const float* __restrict__ g,
                                                 const float* __restrict__ b,
                                                 u16* __restrict__ y) {
  const int row = blockIdx.x;
  const int t = threadIdx.x;
  const float* xr = x + (size_t)row * 1024;
  float4 v = ((const float4*)xr)[t];
  float s  = v.x + v.y + v.z + v.w;
  float s2 = v.x * v.x + v.y * v.y + v.z * v.z + v.w * v.w;
  #pragma unroll
  for (int m = 1; m < 64; m <<= 1) {
    s  += __shfl_xor(s, m);
    s2 += __shfl_xor(s2, m);
  }
  __shared__ float red[8];
  if ((t & 63) == 0) { red[(t >> 6) * 2] = s; red[(t >> 6) * 2 + 1] = s2; }
  __syncthreads();
  s  = red[0] + red[2] + red[4] + red[6];
  s2 = red[1] + red[3] + red[5] + red[7];
  const float mu = s * (1.f / 1024.f);
  const float var = s2 * (1.f / 1024.f) - mu * mu;
  const float rs = rsqrtf(var + 1e-5f);
  float4 gv = ((const float4*)g)[t];
  float4 bv = ((const float4*)b)[t];
  ushort4 o;
  o.x = f2b((v.x - mu) * rs * gv.x + bv.x);
  o.y = f2b((v.y - mu) * rs * gv.y + bv.y);
  o.z = f2b((v.z - mu) * rs * gv.z + bv.z);
  o.w = f2b((v.w - mu) * rs * gv.w + bv.w);
  ((ushort4*)(y + (size_t)row * 1024))[t] = o;
}

// ---------------------------------------------------------------------------
// gemm_out: C[M,N] = A[M,K] @ Bw[N,K]^T, fp32 out = acc + bias + resid.
// 128x128 tile, 8 waves, BK=64, dbuf, XOR swizzle, counted vmcnt, setprio.
// ---------------------------------------------------------------------------
__global__ __launch_bounds__(512, 4) void gemm_out(
    const u16* __restrict__ A, const u16* __restrict__ Bw,
    const float* __restrict__ bias, const float* __restrict__ resid,
    float* __restrict__ out, int N, int K) {
  extern __shared__ u16 lds[];
  const int tid = threadIdx.x;
  const int l = tid & 63, wid = tid >> 6;
  const int li = l & 15, lg = l >> 4;
  const int wr = wid >> 2, wc = wid & 3;
  const int nx = N >> 7;
  const int cpx = gridDim.x >> 3;
  const int v = (blockIdx.x & 7) * cpx + (blockIdx.x >> 3);
  const int by = v / nx, bx = v - by * nx;
  const int m0 = by << 7, n0 = bx << 7;

  const int sr = tid >> 3;
  const int sc = ((tid & 7) ^ (sr & 7)) << 3;
  const int dc = (tid & 7) << 3;
  const int sc0 = (lg * 8) ^ ((li & 7) << 3);
  const int sc1 = sc0 ^ 32;

  f32x4 acc[4][2] = {};

  auto stageA = [&](int kb, int t2) {
    #pragma unroll
    for (int s = 0; s < 2; ++s)
      gload16(A + (size_t)(m0 + s * 64 + sr) * K + t2 * 64 + sc,
              lds + kb * 8192 + (s * 64 + sr) * 64 + dc);
  };
  auto stageB = [&](int kb, int t2) {
    #pragma unroll
    for (int s = 0; s < 2; ++s)
      gload16(Bw + (size_t)(n0 + s * 64 + sr) * K + t2 * 64 + sc,
              lds + 16384 + kb * 8192 + (s * 64 + sr) * 64 + dc);
  };

  const int NT = K >> 6;
  stageA(0, 0); stageB(0, 0);
  __builtin_amdgcn_sched_barrier(0);
  stageA(1, 1); stageB(1, 1);
  __builtin_amdgcn_sched_barrier(0);
  asm volatile("s_waitcnt vmcnt(4)" ::: "memory");
  __builtin_amdgcn_s_barrier();
  __builtin_amdgcn_sched_barrier(0);

  for (int t = 0; t < NT; ++t) {
    const int kb = t & 1;
    const u16* Ab = lds + kb * 8192 + (wr * 64 + li) * 64;
    const u16* Bb = lds + 16384 + kb * 8192 + (wc * 32 + li) * 64;
    bf16x8 a[4], b[2];

    #pragma unroll
    for (int mi = 0; mi < 4; ++mi) a[mi] = *(const bf16x8*)(Ab + mi * 1024 + sc0);
    #pragma unroll
    for (int n = 0; n < 2; ++n)  b[n]  = *(const bf16x8*)(Bb + n * 1024 + sc0);
    __builtin_amdgcn_s_barrier();
    __builtin_amdgcn_s_setprio(1);
    #pragma unroll
    for (int mi = 0; mi < 4; ++mi)
      #pragma unroll
      for (int n = 0; n < 2; ++n)
        acc[mi][n] = __builtin_amdgcn_mfma_f32_16x16x32_bf16(a[mi], b[n], acc[mi][n], 0, 0, 0);
    __builtin_amdgcn_s_setprio(0);
    __builtin_amdgcn_s_barrier();

    #pragma unroll
    for (int mi = 0; mi < 4; ++mi) a[mi] = *(const bf16x8*)(Ab + mi * 1024 + sc1);
    #pragma unroll
    for (int n = 0; n < 2; ++n)  b[n]  = *(const bf16x8*)(Bb + n * 1024 + sc1);
    __builtin_amdgcn_s_barrier();
    __builtin_amdgcn_s_setprio(1);
    #pragma unroll
    for (int mi = 0; mi < 4; ++mi)
      #pragma unroll
      for (int n = 0; n < 2; ++n)
        acc[mi][n] = __builtin_amdgcn_mfma_f32_16x16x32_bf16(a[mi], b[n], acc[mi][n], 0, 0, 0);
    __builtin_amdgcn_s_setprio(0);
    if (t + 2 < NT) {
      stageA(kb, t + 2); stageB(kb, t + 2);
      asm volatile("s_waitcnt vmcnt(4)" ::: "memory");
    } else if (t + 2 == NT) {
      asm volatile("s_waitcnt vmcnt(0)" ::: "memory");
    }
    __builtin_amdgcn_s_barrier();
    __builtin_amdgcn_sched_barrier(0);
  }

  #pragma unroll
  for (int mi = 0; mi < 4; ++mi) {
    const int m = m0 + wr * 64 + mi * 16 + lg * 4;
    #pragma unroll
    for (int n = 0; n < 2; ++n) {
      const int j = n0 + wc * 32 + n * 16 + li;
      const float bj = bias[j];
      #pragma unroll
      for (int rb = 0; rb < 4; ++rb)
        out[(size_t)(m + rb) * N + j] =
            acc[mi][n][rb] + bj + resid[(size_t)(m + rb) * N + j];
    }
  }
}

// ===========================================================================
// 256x256 4-phase K-loop, ONE barrier per phase (4/tile).
// ===========================================================================
#define KLOOP_PROLOGUE()                                                      \
  stageA(0, 0); stageB(0, 0); stageA(1, 0); stageB(1, 0);                     \
  __builtin_amdgcn_sched_barrier(0);                                          \
  stageA(0, 1); stageB(0, 1);                                                 \
  __builtin_amdgcn_sched_barrier(0);                                          \
  asm volatile("s_waitcnt vmcnt(4)" ::: "memory");                            \
  __builtin_amdgcn_s_barrier();                                               \
  __builtin_amdgcn_sched_barrier(0);

#define KLOOP_BODY(NT)                                                        \
  bf16x8 b0[4], b1[4];                                                        \
  for (int t = 0; t < NT; ++t) {                                              \
    const int kb = t & 1;                                                     \
    const u16* Abase0 = lds + (kb * 2 + 0) * 8192 + rowA0;                    \
    const u16* Abase1 = lds + (kb * 2 + 1) * 8192 + rowA0;                    \
    const u16* Bbase  = lds + (kb * 2 + bhn) * 8192 + rowB0;                  \
    bf16x8 a[4];                                                              \
    /* phase 1: (qm0, k0) */                                                  \
    _Pragma("unroll")                                                         \
    for (int j = 0; j < 4; ++j) a[j]  = *(const bf16x8*)(Abase0 + j * 1024 + sc0); \
    _Pragma("unroll")                                                         \
    for (int n = 0; n < 4; ++n) b0[n] = *(const bf16x8*)(Bbase + n * 1024 + sc0); \
    if (t + 1 < NT) stageA(1, t + 1);                                         \
    __builtin_amdgcn_s_setprio(1);                                            \
    _Pragma("unroll")                                                         \
    for (int j = 0; j < 4; ++j)                                               \
      _Pragma("unroll")                                                       \
      for (int n = 0; n < 4; ++n)                                             \
        acc[j][n] = __builtin_amdgcn_mfma_f32_16x16x32_bf16(a[j], b0[n], acc[j][n], 0, 0, 0); \
    __builtin_amdgcn_s_setprio(0);                                            \
    __builtin_amdgcn_s_barrier();                                             \
    /* phase 2: (qm0, k1) */                                                  \
    _Pragma("unroll")                                                         \
    for (int j = 0; j < 4; ++j) a[j]  = *(const bf16x8*)(Abase0 + j * 1024 + sc1); \
    _Pragma("unroll")                                                         \
    for (int n = 0; n < 4; ++n) b1[n] = *(const bf16x8*)(Bbase + n * 1024 + sc1); \
    if (t + 1 < NT) stageB(1, t + 1);                                         \
    __builtin_amdgcn_s_setprio(1);                                            \
    _Pragma("unroll")                                                         \
    for (int j = 0; j < 4; ++j)                                               \
      _Pragma("unroll")                                                       \
      for (int n = 0; n < 4; ++n)                                             \
        acc[j][n] = __builtin_amdgcn_mfma_f32_16x16x32_bf16(a[j], b1[n], acc[j][n], 0, 0, 0); \
    __builtin_amdgcn_s_setprio(0);                                            \
    __builtin_amdgcn_s_barrier();                                             \
    /* phase 3: (qm1, k0) */                                                  \
    _Pragma("unroll")                                                         \
    for (int j = 0; j < 4; ++j) a[j] = *(const bf16x8*)(Abase1 + j * 1024 + sc0); \
    if (t + 2 < NT) stageA(0, t + 2);                                         \
    __builtin_amdgcn_s_setprio(1);                                            \
    _Pragma("unroll")                                                         \
    for (int j = 0; j < 4; ++j)                                               \
      _Pragma("unroll")                                                       \
      for (int n = 0; n < 4; ++n)                                             \
        acc[4 + j][n] = __builtin_amdgcn_mfma_f32_16x16x32_bf16(a[j], b0[n], acc[4 + j][n], 0, 0, 0); \
    __builtin_amdgcn_s_setprio(0);                                            \
    __builtin_amdgcn_s_barrier();                                             \
    /* phase 4: (qm1, k1) */                                                  \
    _Pragma("unroll")                                                         \
    for (int j = 0; j < 4; ++j) a[j] = *(const bf16x8*)(Abase1 + j * 1024 + sc1); \
    if (t + 2 < NT) stageB(0, t + 2);                                         \
    __builtin_amdgcn_s_setprio(1);                                            \
    _Pragma("unroll")                                                         \
    for (int j = 0; j < 4; ++j)                                               \
      _Pragma("unroll")                                                       \
      for (int n = 0; n < 4; ++n)                                             \
        acc[4 + j][n] = __builtin_amdgcn_mfma_f32_16x16x32_bf16(a[j], b1[n], acc[4 + j][n], 0, 0, 0); \
    __builtin_amdgcn_s_setprio(0);                                            \
    if (t < NT - 2)       asm volatile("s_waitcnt vmcnt(4)" ::: "memory");    \
    else if (t == NT - 2) asm volatile("s_waitcnt vmcnt(0)" ::: "memory");    \
    __builtin_amdgcn_s_barrier();                                             \
  }

// ---------------------------------------------------------------------------
// FF1: 256x256 packed-GEGLU GEMM. XCD decode: 8x8 2D chunk per XCD.
// ---------------------------------------------------------------------------
__global__ __launch_bounds__(512, 2) void gemm_ff1(
    const u16* __restrict__ A, const u16* __restrict__ Wp,
    const float* __restrict__ bias, u16* __restrict__ out) {
  extern __shared__ u16 lds[];
  const int tid = threadIdx.x;
  const int l = tid & 63, wid = tid >> 6;
  const int li = l & 15, lg = l >> 4;
  const int wr = wid >> 2, wc = wid & 3;
  const int xcd = blockIdx.x & 7, r = blockIdx.x >> 3;   // r in [0,64)
  const int bx = (xcd & 3) * 8 + (r >> 3);               // [0,32)
  const int by = (xcd >> 2) * 8 + (r & 7);               // [0,16)

  const int lr8 = l >> 3;
  const int scb = ((l & 7) ^ lr8) << 3;
  const int sc0 = (lg * 8) ^ ((li & 7) << 3);
  const int sc1 = sc0 ^ 32;

  const int rowA0 = (wr * 64 + li) * 64;
  const int rowB0 = 32768 + ((wc & 1) * 64 + li) * 64;
  const int bhn = wc >> 1;

  f32x4 acc[8][4] = {};

  auto stageA = [&](int h, int t2) {
    const int kb2 = t2 & 1;
    #pragma unroll
    for (int s = 0; s < 2; ++s) {
      const u16* g = A + (size_t)(by * 256 + s * 128 + h * 64 + wid * 8 + lr8) * 1024
                       + t2 * 64 + scb;
      u16* d = lds + (kb2 * 2 + h) * 8192 + s * 4096 + wid * 512;
      gload16(g, d);
    }
  };
  auto stageB = [&](int h, int t2) {
    const int kb2 = t2 & 1;
    #pragma unroll
    for (int s = 0; s < 2; ++s) {
      const u16* g = Wp + (size_t)(bx * 256 + h * 128 + s * 64 + wid * 8 + lr8) * 1024
                        + t2 * 64 + scb;
      u16* d = lds + 32768 + (kb2 * 2 + h) * 8192 + s * 4096 + wid * 512;
      gload16(g, d);
    }
  };

  KLOOP_PROLOGUE()
  KLOOP_BODY(16)

  #pragma unroll
  for (int nj = 0; nj < 2; ++nj) {
    const int c = bx * 128 + wc * 32 + nj * 16 + li;
    const float ba = bias[c];
    const float bg = bias[4096 + c];
    #pragma unroll
    for (int mi = 0; mi < 8; ++mi) {
      #pragma unroll
      for (int rb = 0; rb < 4; ++rb) {
        const float av = acc[mi][2 * nj][rb] + ba;
        const float gv = acc[mi][2 * nj + 1][rb] + bg;
        out[(size_t)(by * 256 + wr * 128 + mi * 16 + lg * 4 + rb) * 4096 + c]
            = f2b(av * gelu_fast(gv));
      }
    }
  }
}

// ---------------------------------------------------------------------------
// QKV: 256x256 4-phase GEMM, N=3072. XCD decode: 4by x 6bx chunk per XCD.
// ---------------------------------------------------------------------------
__global__ __launch_bounds__(512, 2) void gemm_qkv(
    const u16* __restrict__ A, const u16* __restrict__ Wp,
    u16* __restrict__ outp) {
  extern __shared__ u16 lds[];
  const int tid = threadIdx.x;
  const int l = tid & 63, wid = tid >> 6;
  const int li = l & 15, lg = l >> 4;
  const int wr = wid >> 2, wc = wid & 3;
  const int xcd = blockIdx.x & 7, r = blockIdx.x >> 3;   // r in [0,24)
  const int by = (xcd >> 1) * 4 + r / 6;                 // [0,16)
  const int bx = (xcd & 1) * 6 + r % 6;                  // [0,12)

  const int lr8 = l >> 3;
  const int scb = ((l & 7) ^ lr8) << 3;
  const int sc0 = (lg * 8) ^ ((li & 7) << 3);
  const int sc1 = sc0 ^ 32;

  const int rowA0 = (wr * 64 + li) * 64;
  const int rowB0 = 32768 + ((wc & 1) * 64 + li) * 64;
  const int bhn = wc >> 1;

  f32x4 acc[8][4] = {};

  auto stageA = [&](int h, int t2) {
    const int kb2 = t2 & 1;
    #pragma unroll
    for (int s = 0; s < 2; ++s) {
      const u16* g = A + (size_t)(by * 256 + s * 128 + h * 64 + wid * 8 + lr8) * 1024
                       + t2 * 64 + scb;
      u16* d = lds + (kb2 * 2 + h) * 8192 + s * 4096 + wid * 512;
      gload16(g, d);
    }
  };
  auto stageB = [&](int h, int t2) {
    const int kb2 = t2 & 1;
    #pragma unroll
    for (int s = 0; s < 2; ++s) {
      const u16* g = Wp + (size_t)(bx * 256 + h * 128 + s * 64 + wid * 8 + lr8) * 1024
                        + t2 * 64 + scb;
      u16* d = lds + 32768 + (kb2 * 2 + h) * 8192 + s * 4096 + wid * 512;
      gload16(g, d);
    }
  };

  KLOOP_PROLOGUE()
  KLOOP_BODY(16)

  #pragma unroll
  for (int mi = 0; mi < 8; ++mi) {
    const int mbase = by * 256 + wr * 128 + mi * 16 + lg * 4;
    #pragma unroll
    for (int ni = 0; ni < 4; ++ni) {
      const int j = bx * 256 + wc * 64 + ni * 16 + li;
      f32x4 a = acc[mi][ni];
      const int sec = j >> 10, jj = j & 1023;
      const int h = jj >> 6, dd = jj & 63;
      u16* base = outp + (size_t)sec * 4194304;
      if (sec == 0) {
        #pragma unroll
        for (int rb = 0; rb < 4; ++rb) {
          const int m = mbase + rb;
          const int bb = m >> 11, n = m & 2047;
          base[(((size_t)bb * 16 + h) * 2048 + n) * 64 + dd] =
              f2b(a[rb] * 0.18033688011112042f);
        }
      } else if (sec == 1) {
        #pragma unroll
        for (int rb = 0; rb < 4; ++rb) {
          const int m = mbase + rb;
          const int bb = m >> 11, n = m & 2047;
          base[(((size_t)bb * 16 + h) * 2048 + n) * 64 + (dd ^ ((n & 7) << 3))] =
              f2b(a[rb]);
        }
      } else {
        const int bb = mbase >> 11, n = mbase & 2047;
        const int ng = n & ~63, nl = n & 63;
        const int nl2 = (nl & 51) | ((nl & 4) << 1) | ((nl & 8) >> 1);
        const int col = ng | (nl2 ^ ((dd & 7) << 3));
        ushort4 pk;
        pk.x = f2b(a[0]); pk.y = f2b(a[1]); pk.z = f2b(a[2]); pk.w = f2b(a[3]);
        *(ushort4*)&base[(((size_t)bb * 16 + h) * 64 + dd) * 2048 + col] = pk;
      }
    }
  }
}

// ---------------------------------------------------------------------------
// Flash attention, swapped-operand 32x32 MFMA, STATIC-SHIFT softmax.
// 3-buffer staging, counted vmcnt, one barrier/tile, setprio MFMA clusters.
// XCD-chunked decode: each XCD owns 4 complete heads (KV 2MB, L2-resident).
// ---------------------------------------------------------------------------
__global__ __launch_bounds__(256, 2) void attn_fwd(
    const u16* __restrict__ Q, const u16* __restrict__ K,
    const u16* __restrict__ Vt, u16* __restrict__ Out) {
  __shared__ u16 smem[3][8192];
  const int tid = threadIdx.x;
  const int l = tid & 63, w = tid >> 6;
  const int lo = l & 31, hi = l >> 5, l7 = l & 7;
  const int v = (blockIdx.x & 7) * 64 + (blockIdx.x >> 3);  // XCD-chunked
  const int bh = v >> 4, qt = v & 15;
  const int b_ = bh >> 4, h = bh & 15;

  const u16* Qg = Q + ((size_t)bh * 2048 + qt * 128 + w * 32 + lo) * 64;
  const u16* Kg = K + (size_t)bh * 2048 * 64;
  const u16* Vg = Vt + (size_t)bh * 64 * 2048;

  bf16x8 qf[4];
  #pragma unroll
  for (int d = 0; d < 4; ++d) qf[d] = *(const bf16x8*)&Qg[d * 16 + hi * 8];

  f32x16 o0 = {}, o1 = {};
  float lrow = 0.f;

  auto stage = [&](int buf, int jt) {
    #pragma unroll
    for (int i = 0; i < 2; ++i)
      gload16(Kg + (size_t)jt * 4096 + i * 2048 + tid * 8,
              &smem[buf][i * 2048 + w * 512]);
    #pragma unroll
    for (int i = 0; i < 2; ++i)
      gload16(Vg + (size_t)(w * 8 + (l >> 3) + i * 32) * 2048 + jt * 64 + l7 * 8,
              &smem[buf][4096 + i * 2048 + w * 512]);
  };

  // pin VMEM issue order: Q(4), tile0(4), tile1(4) — vmcnt counts issue order
  __builtin_amdgcn_sched_barrier(0);
  stage(0, 0);
  __builtin_amdgcn_sched_barrier(0);
  stage(1, 1);
  __builtin_amdgcn_sched_barrier(0);

  int cur = 0, pre = 2;
  for (int jt = 0; jt < 32; ++jt) {
    if (jt == 0)      asm volatile("s_waitcnt vmcnt(8)" ::: "memory");
    else if (jt < 31) asm volatile("s_waitcnt vmcnt(4)" ::: "memory");
    else              asm volatile("s_waitcnt vmcnt(0)" ::: "memory");
    __builtin_amdgcn_s_barrier();
    __builtin_amdgcn_sched_barrier(0);
    if (jt + 2 < 32) stage(pre, jt + 2);

    const u16* Kl = &smem[cur][0];
    const u16* Vl = &smem[cur][4096];

    bf16x8 kf[4][2], vf0[4], vf1[4];
    #pragma unroll
    for (int dc = 0; dc < 4; ++dc) {
      const int col = (dc * 16 + hi * 8) ^ (l7 << 3);
      kf[dc][0] = *(const bf16x8*)&Kl[lo * 64 + col];
      kf[dc][1] = *(const bf16x8*)&Kl[(32 + lo) * 64 + col];
      vf0[dc]   = *(const bf16x8*)&Vl[lo * 64 + col];
      vf1[dc]   = *(const bf16x8*)&Vl[(32 + lo) * 64 + col];
    }

    f32x16 st[2] = {};
    __builtin_amdgcn_s_setprio(1);
    #pragma unroll
    for (int dc = 0; dc < 4; ++dc) {
      st[0] = __builtin_amdgcn_mfma_f32_32x32x16_bf16(kf[dc][0], qf[dc], st[0], 0, 0, 0);
      st[1] = __builtin_amdgcn_mfma_f32_32x32x16_bf16(kf[dc][1], qf[dc], st[1], 0, 0, 0);
    }
    __builtin_amdgcn_s_setprio(0);

    // P = 2^(st - 8): no max tracking, no rescale (logits bounded)
    float p[32], sm[16];
    #pragma unroll
    for (int r = 0; r < 16; ++r) p[r]      = exp2_raw(st[0][r] - 8.f);
    #pragma unroll
    for (int r = 0; r < 16; ++r) p[16 + r] = exp2_raw(st[1][r] - 8.f);
    #pragma unroll
    for (int r = 0; r < 16; ++r) sm[r] = p[r] + p[16 + r];
    #pragma unroll
    for (int s2 = 8; s2 >= 1; s2 >>= 1)
      #pragma unroll
      for (int r = 0; r < s2; ++r) sm[r] += sm[r + s2];
    lrow += sm[0] + __shfl_xor(sm[0], 32);

    // pack P -> B-fragments (order matches V key-bitswap storage)
    bf16x8 pf[4];
    #pragma unroll
    for (int kp = 0; kp < 4; ++kp) {
      u32x4 wv;
      #pragma unroll
      for (int t2 = 0; t2 < 4; ++t2)
        wv[t2] = cvtpk(p[(kp >> 1) * 16 + (kp & 1) * 8 + t2 * 2],
                       p[(kp >> 1) * 16 + (kp & 1) * 8 + t2 * 2 + 1]);
      union { u32x4 a; bf16x8 b; } cc; cc.a = wv;
      pf[kp] = cc.b;
    }

    __builtin_amdgcn_s_setprio(1);
    #pragma unroll
    for (int kp = 0; kp < 4; ++kp) {
      o0 = __builtin_amdgcn_mfma_f32_32x32x16_bf16(vf0[kp], pf[kp], o0, 0, 0, 0);
      o1 = __builtin_amdgcn_mfma_f32_32x32x16_bf16(vf1[kp], pf[kp], o1, 0, 0, 0);
    }
    __builtin_amdgcn_s_setprio(0);

    cur = (cur == 2) ? 0 : cur + 1;
    pre = (pre == 2) ? 0 : pre + 1;
  }

  const float inv = 1.f / lrow;
  u16* Ob = Out + ((size_t)b_ * 2048 + qt * 128 + w * 32 + lo) * 1024 + h * 64;
  #pragma unroll
  for (int dd = 0; dd < 2; ++dd) {
    #pragma unroll
    for (int R = 0; R < 4; ++R) {
      ushort4 pk;
      const f32x16 oo = dd ? o1 : o0;
      pk.x = f2b(oo[4 * R + 0] * inv); pk.y = f2b(oo[4 * R + 1] * inv);
      pk.z = f2b(oo[4 * R + 2] * inv); pk.w = f2b(oo[4 * R + 3] * inv);
      *(ushort4*)&Ob[dd * 32 + 8 * R + 4 * hi] = pk;
    }
  }
}

// ---------------------------------------------------------------------------
// Host launch
// ---------------------------------------------------------------------------
extern "C" void kernel_launch(void* const* d_in, const int* in_sizes, int n_in,
                              void* d_out, int out_size, void* d_ws, size_t ws_size,
                              hipStream_t stream) {
  const float* x    = (const float*)d_in[0];
  const float* ln1g = (const float*)d_in[1];
  const float* ln1b = (const float*)d_in[2];
  const float* wq1  = (const float*)d_in[3];
  const float* wk1  = (const float*)d_in[4];
  const float* wv1  = (const float*)d_in[5];
  const float* wo1  = (const float*)d_in[6];
  const float* bo1  = (const float*)d_in[7];
  const float* ln2g = (const float*)d_in[8];
  const float* ln2b = (const float*)d_in[9];
  const float* wq2  = (const float*)d_in[10];
  const float* wk2  = (const float*)d_in[11];
  const float* wv2  = (const float*)d_in[12];
  const float* wo2  = (const float*)d_in[13];
  const float* bo2  = (const float*)d_in[14];
  const float* ln3g = (const float*)d_in[15];
  const float* ln3b = (const float*)d_in[16];
  const float* wff1 = (const float*)d_in[17];
  const float* bff1 = (const float*)d_in[18];
  const float* wff2 = (const float*)d_in[19];
  const float* bff2 = (const float*)d_in[20];

  char* ws = (char*)d_ws;
  const size_t MB = 1024 * 1024;
  u16* wqkv1b = (u16*)(ws + 0 * MB);
  u16* wo1b   = (u16*)(ws + 6 * MB);
  u16* wqkv2b = (u16*)(ws + 8 * MB);
  u16* wo2b   = (u16*)(ws + 14 * MB);
  u16* wff1p  = (u16*)(ws + 16 * MB);
  u16* wff2b  = (u16*)(ws + 32 * MB);
  u16* xn     = (u16*)(ws + 40 * MB);
  u16* Qb     = (u16*)(ws + 48 * MB);
  float* x1   = (float*)(ws + 72 * MB);
  float* x2   = (float*)(ws + 88 * MB);
  u16* hact   = (u16*)(ws + 48 * MB);
  u16* Kb  = Qb + 4194304;
  u16* Vtb = Qb + 8388608;

  hipFuncSetAttribute((const void*)gemm_ff1,
                      hipFuncAttributeMaxDynamicSharedMemorySize, 131072);
  hipFuncSetAttribute((const void*)gemm_qkv,
                      hipFuncAttributeMaxDynamicSharedMemorySize, 131072);
  hipFuncSetAttribute((const void*)gemm_out,
                      hipFuncAttributeMaxDynamicSharedMemorySize, 65536);

  castall<<<20480, 256, 0, stream>>>(wq1, wk1, wv1, wo1, wq2, wk2, wv2, wo2,
                                     wff1, wff2,
                                     wqkv1b, wo1b, wqkv2b, wo2b, wff1p, wff2b);

  // ---- attention block 1 ----
  ln_kernel<<<4096, 256, 0, stream>>>(x, ln1g, ln1b, xn);
  gemm_qkv<<<192, 512, 131072, stream>>>(xn, wqkv1b, Qb);
  attn_fwd<<<512, 256, 0, stream>>>(Qb, Kb, Vtb, xn);
  gemm_out<<<256, 512, 65536, stream>>>(xn, wo1b, bo1, x, x1, 1024, 1024);

  // ---- attention block 2 ----
  ln_kernel<<<4096, 256, 0, stream>>>(x1, ln2g, ln2b, xn);
  gemm_qkv<<<192, 512, 131072, stream>>>(xn, wqkv2b, Qb);
  attn_fwd<<<512, 256, 0, stream>>>(Qb, Kb, Vtb, xn);
  gemm_out<<<256, 512, 65536, stream>>>(xn, wo2b, bo2, x1, x2, 1024, 1024);

  // ---- GEGLU FF ----
  ln_kernel<<<4096, 256, 0, stream>>>(x2, ln3g, ln3b, xn);
  gemm_ff1<<<512, 512, 131072, stream>>>(xn, wff1p, bff1, hact);
  gemm_out<<<256, 512, 65536, stream>>>(hact, wff2b, bff2, x2, (float*)d_out, 1024, 4096);
}

// Round 12
// 360.605 us; speedup vs baseline: 1.1709x; 1.0095x over previous
//
#include <hip/hip_runtime.h>
#include <hip/hip_bf16.h>

using bf16x8 = __attribute__((ext_vector_type(8))) short;
using f32x4  = __attribute__((ext_vector_type(4))) float;
using f32x16 = __attribute__((ext_vector_type(16))) float;
typedef unsigned int u32;
typedef unsigned short u16;
using u32x4 = __attribute__((ext_vector_type(4))) u32;

__device__ __forceinline__ u16 f2b(float f) {
  union { float f; u32 u; } v; v.f = f;
  return (u16)((v.u + 0x7FFFu + ((v.u >> 16) & 1u)) >> 16);
}

__device__ __forceinline__ u32 cvtpk(float lo, float hi) {
  u32 r;
  asm("v_cvt_pk_bf16_f32 %0, %1, %2" : "=v"(r) : "v"(lo), "v"(hi));
  return r;
}

__device__ __forceinline__ float exp2_raw(float x) {
  float r;
  asm("v_exp_f32 %0, %1" : "=v"(r) : "v"(x));
  return r;
}

__device__ __forceinline__ void gload16(const void* g, void* l) {
  __builtin_amdgcn_global_load_lds((const __attribute__((address_space(1))) u32*)g,
                                   (__attribute__((address_space(3))) u32*)l, 16, 0, 0);
}

// gelu via tanh approx: x * u/(u+1), u = 2^(2*0.79788456*log2e*(x+0.044715x^3))
__device__ __forceinline__ float gelu_fast(float x) {
  const float x2 = x * x;
  const float t = x * fmaf(0.044715f, x2, 1.f);
  const float u = exp2f(2.3022080f * t);
  return x * u * __builtin_amdgcn_rcpf(u + 1.f);
}

// ---------------------------------------------------------------------------
// Fused weight cast fp32 -> bf16 (QKV packed; FF1 a/gate interleaved per 16)
// ---------------------------------------------------------------------------
__global__ __launch_bounds__(256) void castall(
    const float* __restrict__ wq1, const float* __restrict__ wk1,
    const float* __restrict__ wv1, const float* __restrict__ wo1,
    const float* __restrict__ wq2, const float* __restrict__ wk2,
    const float* __restrict__ wv2, const float* __restrict__ wo2,
    const float* __restrict__ wff1, const float* __restrict__ wff2,
    u16* __restrict__ qkv1, u16* __restrict__ o1,
    u16* __restrict__ qkv2, u16* __restrict__ o2,
    u16* __restrict__ ff1p, u16* __restrict__ ff2) {
  const long e = ((long)blockIdx.x * 256 + threadIdx.x) * 4;
  constexpr long M1 = 1l << 20;
  const float* s; u16* d;
  if (e < 3 * M1) {
    s = (e < M1 ? wq1 + e : (e < 2 * M1 ? wk1 + (e - M1) : wv1 + (e - 2 * M1)));
    d = qkv1 + e;
  } else if (e < 4 * M1) {
    s = wo1 + (e - 3 * M1); d = o1 + (e - 3 * M1);
  } else if (e < 7 * M1) {
    long r = e - 4 * M1;
    s = (r < M1 ? wq2 + r : (r < 2 * M1 ? wk2 + (r - M1) : wv2 + (r - 2 * M1)));
    d = qkv2 + r;
  } else if (e < 8 * M1) {
    s = wo2 + (e - 7 * M1); d = o2 + (e - 7 * M1);
  } else if (e < 16 * M1) {
    long r = e - 8 * M1;
    long p = r >> 10, col = r & 1023;
    long g = p >> 5, rr = p & 31;
    long lr = (rr < 16) ? (g << 4) + rr : 4096 + (g << 4) + (rr - 16);
    s = wff1 + (lr << 10) + col; d = ff1p + r;
  } else {
    long r = e - 16 * M1;
    s = wff2 + r; d = ff2 + r;
  }
  float4 v = *(const float4*)s;
  ushort4 o;
  o.x = f2b(v.x); o.y = f2b(v.y); o.z = f2b(v.z); o.w = f2b(v.w);
  *(ushort4*)d = o;
}

// ---------------------------------------------------------------------------
// LayerNorm: one block per row of 1024, fp32 in -> bf16 out
// ---------------------------------------------------------------------------
__global__ __launch_bounds__(256) void ln_kernel(const float* __restrict__ x,
                                                 const float* __restrict__ g,
                                                 const float* __restrict__ b,
                                                 u16* __restrict__ y) {
  const int row = blockIdx.x;
  const int t = threadIdx.x;
  const float* xr = x + (size_t)row * 1024;
  float4 v = ((const float4*)xr)[t];
  float s  = v.x + v.y + v.z + v.w;
  float s2 = v.x * v.x + v.y * v.y + v.z * v.z + v.w * v.w;
  #pragma unroll
  for (int m = 1; m < 64; m <<= 1) {
    s  += __shfl_xor(s, m);
    s2 += __shfl_xor(s2, m);
  }
  __shared__ float red[8];
  if ((t & 63) == 0) { red[(t >> 6) * 2] = s; red[(t >> 6) * 2 + 1] = s2; }
  __syncthreads();
  s  = red[0] + red[2] + red[4] + red[6];
  s2 = red[1] + red[3] + red[5] + red[7];
  const float mu = s * (1.f / 1024.f);
  const float var = s2 * (1.f / 1024.f) - mu * mu;
  const float rs = rsqrtf(var + 1e-5f);
  float4 gv = ((const float4*)g)[t];
  float4 bv = ((const float4*)b)[t];
  ushort4 o;
  o.x = f2b((v.x - mu) * rs * gv.x + bv.x);
  o.y = f2b((v.y - mu) * rs * gv.y + bv.y);
  o.z = f2b((v.z - mu) * rs * gv.z + bv.z);
  o.w = f2b((v.w - mu) * rs * gv.w + bv.w);
  ((ushort4*)(y + (size_t)row * 1024))[t] = o;
}

// ---------------------------------------------------------------------------
// gemm_out: C[M,N] = A[M,K] @ Bw[N,K]^T, fp32 out = acc + bias + resid.
// 128x128 tile, 8 waves, BK=64, dbuf, XOR swizzle, counted vmcnt, setprio.
// ---------------------------------------------------------------------------
__global__ __launch_bounds__(512, 4) void gemm_out(
    const u16* __restrict__ A, const u16* __restrict__ Bw,
    const float* __restrict__ bias, const float* __restrict__ resid,
    float* __restrict__ out, int N, int K) {
  extern __shared__ u16 lds[];
  const int tid = threadIdx.x;
  const int l = tid & 63, wid = tid >> 6;
  const int li = l & 15, lg = l >> 4;
  const int wr = wid >> 2, wc = wid & 3;
  const int nx = N >> 7;
  const int cpx = gridDim.x >> 3;
  const int v = (blockIdx.x & 7) * cpx + (blockIdx.x >> 3);
  const int by = v / nx, bx = v - by * nx;
  const int m0 = by << 7, n0 = bx << 7;

  const int sr = tid >> 3;
  const int sc = ((tid & 7) ^ (sr & 7)) << 3;
  const int dc = (tid & 7) << 3;
  const int sc0 = (lg * 8) ^ ((li & 7) << 3);
  const int sc1 = sc0 ^ 32;

  f32x4 acc[4][2] = {};

  auto stageA = [&](int kb, int t2) {
    #pragma unroll
    for (int s = 0; s < 2; ++s)
      gload16(A + (size_t)(m0 + s * 64 + sr) * K + t2 * 64 + sc,
              lds + kb * 8192 + (s * 64 + sr) * 64 + dc);
  };
  auto stageB = [&](int kb, int t2) {
    #pragma unroll
    for (int s = 0; s < 2; ++s)
      gload16(Bw + (size_t)(n0 + s * 64 + sr) * K + t2 * 64 + sc,
              lds + 16384 + kb * 8192 + (s * 64 + sr) * 64 + dc);
  };

  const int NT = K >> 6;
  stageA(0, 0); stageB(0, 0);
  __builtin_amdgcn_sched_barrier(0);
  stageA(1, 1); stageB(1, 1);
  __builtin_amdgcn_sched_barrier(0);
  asm volatile("s_waitcnt vmcnt(4)" ::: "memory");
  __builtin_amdgcn_s_barrier();
  __builtin_amdgcn_sched_barrier(0);

  for (int t = 0; t < NT; ++t) {
    const int kb = t & 1;
    const u16* Ab = lds + kb * 8192 + (wr * 64 + li) * 64;
    const u16* Bb = lds + 16384 + kb * 8192 + (wc * 32 + li) * 64;
    bf16x8 a[4], b[2];

    #pragma unroll
    for (int mi = 0; mi < 4; ++mi) a[mi] = *(const bf16x8*)(Ab + mi * 1024 + sc0);
    #pragma unroll
    for (int n = 0; n < 2; ++n)  b[n]  = *(const bf16x8*)(Bb + n * 1024 + sc0);
    __builtin_amdgcn_s_barrier();
    __builtin_amdgcn_s_setprio(1);
    #pragma unroll
    for (int mi = 0; mi < 4; ++mi)
      #pragma unroll
      for (int n = 0; n < 2; ++n)
        acc[mi][n] = __builtin_amdgcn_mfma_f32_16x16x32_bf16(a[mi], b[n], acc[mi][n], 0, 0, 0);
    __builtin_amdgcn_s_setprio(0);
    __builtin_amdgcn_s_barrier();

    #pragma unroll
    for (int mi = 0; mi < 4; ++mi) a[mi] = *(const bf16x8*)(Ab + mi * 1024 + sc1);
    #pragma unroll
    for (int n = 0; n < 2; ++n)  b[n]  = *(const bf16x8*)(Bb + n * 1024 + sc1);
    __builtin_amdgcn_s_barrier();
    __builtin_amdgcn_s_setprio(1);
    #pragma unroll
    for (int mi = 0; mi < 4; ++mi)
      #pragma unroll
      for (int n = 0; n < 2; ++n)
        acc[mi][n] = __builtin_amdgcn_mfma_f32_16x16x32_bf16(a[mi], b[n], acc[mi][n], 0, 0, 0);
    __builtin_amdgcn_s_setprio(0);
    if (t + 2 < NT) {
      stageA(kb, t + 2); stageB(kb, t + 2);
      asm volatile("s_waitcnt vmcnt(4)" ::: "memory");
    } else if (t + 2 == NT) {
      asm volatile("s_waitcnt vmcnt(0)" ::: "memory");
    }
    __builtin_amdgcn_s_barrier();
    __builtin_amdgcn_sched_barrier(0);
  }

  #pragma unroll
  for (int mi = 0; mi < 4; ++mi) {
    const int m = m0 + wr * 64 + mi * 16 + lg * 4;
    #pragma unroll
    for (int n = 0; n < 2; ++n) {
      const int j = n0 + wc * 32 + n * 16 + li;
      const float bj = bias[j];
      #pragma unroll
      for (int rb = 0; rb < 4; ++rb)
        out[(size_t)(m + rb) * N + j] =
            acc[mi][n][rb] + bj + resid[(size_t)(m + rb) * N + j];
    }
  }
}

// ===========================================================================
// 256x256 4-phase K-loop, ONE barrier per phase (4/tile).
// ===========================================================================
#define KLOOP_PROLOGUE()                                                      \
  stageA(0, 0); stageB(0, 0); stageA(1, 0); stageB(1, 0);                     \
  __builtin_amdgcn_sched_barrier(0);                                          \
  stageA(0, 1); stageB(0, 1);                                                 \
  __builtin_amdgcn_sched_barrier(0);                                          \
  asm volatile("s_waitcnt vmcnt(4)" ::: "memory");                            \
  __builtin_amdgcn_s_barrier();                                               \
  __builtin_amdgcn_sched_barrier(0);

#define KLOOP_BODY(NT)                                                        \
  bf16x8 b0[4], b1[4];                                                        \
  for (int t = 0; t < NT; ++t) {                                              \
    const int kb = t & 1;                                                     \
    const u16* Abase0 = lds + (kb * 2 + 0) * 8192 + rowA0;                    \
    const u16* Abase1 = lds + (kb * 2 + 1) * 8192 + rowA0;                    \
    const u16* Bbase  = lds + (kb * 2 + bhn) * 8192 + rowB0;                  \
    bf16x8 a[4];                                                              \
    /* phase 1: (qm0, k0) */                                                  \
    _Pragma("unroll")                                                         \
    for (int j = 0; j < 4; ++j) a[j]  = *(const bf16x8*)(Abase0 + j * 1024 + sc0); \
    _Pragma("unroll")                                                         \
    for (int n = 0; n < 4; ++n) b0[n] = *(const bf16x8*)(Bbase + n * 1024 + sc0); \
    if (t + 1 < NT) stageA(1, t + 1);                                         \
    __builtin_amdgcn_s_setprio(1);                                            \
    _Pragma("unroll")                                                         \
    for (int j = 0; j < 4; ++j)                                               \
      _Pragma("unroll")                                                       \
      for (int n = 0; n < 4; ++n)                                             \
        acc[j][n] = __builtin_amdgcn_mfma_f32_16x16x32_bf16(a[j], b0[n], acc[j][n], 0, 0, 0); \
    __builtin_amdgcn_s_setprio(0);                                            \
    __builtin_amdgcn_s_barrier();                                             \
    /* phase 2: (qm0, k1) */                                                  \
    _Pragma("unroll")                                                         \
    for (int j = 0; j < 4; ++j) a[j]  = *(const bf16x8*)(Abase0 + j * 1024 + sc1); \
    _Pragma("unroll")                                                         \
    for (int n = 0; n < 4; ++n) b1[n] = *(const bf16x8*)(Bbase + n * 1024 + sc1); \
    if (t + 1 < NT) stageB(1, t + 1);                                         \
    __builtin_amdgcn_s_setprio(1);                                            \
    _Pragma("unroll")                                                         \
    for (int j = 0; j < 4; ++j)                                               \
      _Pragma("unroll")                                                       \
      for (int n = 0; n < 4; ++n)                                             \
        acc[j][n] = __builtin_amdgcn_mfma_f32_16x16x32_bf16(a[j], b1[n], acc[j][n], 0, 0, 0); \
    __builtin_amdgcn_s_setprio(0);                                            \
    __builtin_amdgcn_s_barrier();                                             \
    /* phase 3: (qm1, k0) */                                                  \
    _Pragma("unroll")                                                         \
    for (int j = 0; j < 4; ++j) a[j] = *(const bf16x8*)(Abase1 + j * 1024 + sc0); \
    if (t + 2 < NT) stageA(0, t + 2);                                         \
    __builtin_amdgcn_s_setprio(1);                                            \
    _Pragma("unroll")                                                         \
    for (int j = 0; j < 4; ++j)                                               \
      _Pragma("unroll")                                                       \
      for (int n = 0; n < 4; ++n)                                             \
        acc[4 + j][n] = __builtin_amdgcn_mfma_f32_16x16x32_bf16(a[j], b0[n], acc[4 + j][n], 0, 0, 0); \
    __builtin_amdgcn_s_setprio(0);                                            \
    __builtin_amdgcn_s_barrier();                                             \
    /* phase 4: (qm1, k1) */                                                  \
    _Pragma("unroll")                                                         \
    for (int j = 0; j < 4; ++j) a[j] = *(const bf16x8*)(Abase1 + j * 1024 + sc1); \
    if (t + 2 < NT) stageB(0, t + 2);                                         \
    __builtin_amdgcn_s_setprio(1);                                            \
    _Pragma("unroll")                                                         \
    for (int j = 0; j < 4; ++j)                                               \
      _Pragma("unroll")                                                       \
      for (int n = 0; n < 4; ++n)                                             \
        acc[4 + j][n] = __builtin_amdgcn_mfma_f32_16x16x32_bf16(a[j], b1[n], acc[4 + j][n], 0, 0, 0); \
    __builtin_amdgcn_s_setprio(0);                                            \
    if (t < NT - 2)       asm volatile("s_waitcnt vmcnt(4)" ::: "memory");    \
    else if (t == NT - 2) asm volatile("s_waitcnt vmcnt(0)" ::: "memory");    \
    __builtin_amdgcn_s_barrier();                                             \
  }

// ---------------------------------------------------------------------------
// FF1: 256x256 packed-GEGLU GEMM. XCD decode: 8x8 2D chunk per XCD.
// ---------------------------------------------------------------------------
__global__ __launch_bounds__(512, 2) void gemm_ff1(
    const u16* __restrict__ A, const u16* __restrict__ Wp,
    const float* __restrict__ bias, u16* __restrict__ out) {
  extern __shared__ u16 lds[];
  const int tid = threadIdx.x;
  const int l = tid & 63, wid = tid >> 6;
  const int li = l & 15, lg = l >> 4;
  const int wr = wid >> 2, wc = wid & 3;
  const int xcd = blockIdx.x & 7, r = blockIdx.x >> 3;   // r in [0,64)
  const int bx = (xcd & 3) * 8 + (r >> 3);               // [0,32)
  const int by = (xcd >> 2) * 8 + (r & 7);               // [0,16)

  const int lr8 = l >> 3;
  const int scb = ((l & 7) ^ lr8) << 3;
  const int sc0 = (lg * 8) ^ ((li & 7) << 3);
  const int sc1 = sc0 ^ 32;

  const int rowA0 = (wr * 64 + li) * 64;
  const int rowB0 = 32768 + ((wc & 1) * 64 + li) * 64;
  const int bhn = wc >> 1;

  f32x4 acc[8][4] = {};

  auto stageA = [&](int h, int t2) {
    const int kb2 = t2 & 1;
    #pragma unroll
    for (int s = 0; s < 2; ++s) {
      const u16* g = A + (size_t)(by * 256 + s * 128 + h * 64 + wid * 8 + lr8) * 1024
                       + t2 * 64 + scb;
      u16* d = lds + (kb2 * 2 + h) * 8192 + s * 4096 + wid * 512;
      gload16(g, d);
    }
  };
  auto stageB = [&](int h, int t2) {
    const int kb2 = t2 & 1;
    #pragma unroll
    for (int s = 0; s < 2; ++s) {
      const u16* g = Wp + (size_t)(bx * 256 + h * 128 + s * 64 + wid * 8 + lr8) * 1024
                        + t2 * 64 + scb;
      u16* d = lds + 32768 + (kb2 * 2 + h) * 8192 + s * 4096 + wid * 512;
      gload16(g, d);
    }
  };

  KLOOP_PROLOGUE()
  KLOOP_BODY(16)

  #pragma unroll
  for (int nj = 0; nj < 2; ++nj) {
    const int c = bx * 128 + wc * 32 + nj * 16 + li;
    const float ba = bias[c];
    const float bg = bias[4096 + c];
    #pragma unroll
    for (int mi = 0; mi < 8; ++mi) {
      #pragma unroll
      for (int rb = 0; rb < 4; ++rb) {
        const float av = acc[mi][2 * nj][rb] + ba;
        const float gv = acc[mi][2 * nj + 1][rb] + bg;
        out[(size_t)(by * 256 + wr * 128 + mi * 16 + lg * 4 + rb) * 4096 + c]
            = f2b(av * gelu_fast(gv));
      }
    }
  }
}

// ---------------------------------------------------------------------------
// QKV: 256x256 4-phase GEMM, N=3072. XCD decode: 4by x 6bx chunk per XCD.
// ---------------------------------------------------------------------------
__global__ __launch_bounds__(512, 2) void gemm_qkv(
    const u16* __restrict__ A, const u16* __restrict__ Wp,
    u16* __restrict__ outp) {
  extern __shared__ u16 lds[];
  const int tid = threadIdx.x;
  const int l = tid & 63, wid = tid >> 6;
  const int li = l & 15, lg = l >> 4;
  const int wr = wid >> 2, wc = wid & 3;
  const int xcd = blockIdx.x & 7, r = blockIdx.x >> 3;   // r in [0,24)
  const int by = (xcd >> 1) * 4 + r / 6;                 // [0,16)
  const int bx = (xcd & 1) * 6 + r % 6;                  // [0,12)

  const int lr8 = l >> 3;
  const int scb = ((l & 7) ^ lr8) << 3;
  const int sc0 = (lg * 8) ^ ((li & 7) << 3);
  const int sc1 = sc0 ^ 32;

  const int rowA0 = (wr * 64 + li) * 64;
  const int rowB0 = 32768 + ((wc & 1) * 64 + li) * 64;
  const int bhn = wc >> 1;

  f32x4 acc[8][4] = {};

  auto stageA = [&](int h, int t2) {
    const int kb2 = t2 & 1;
    #pragma unroll
    for (int s = 0; s < 2; ++s) {
      const u16* g = A + (size_t)(by * 256 + s * 128 + h * 64 + wid * 8 + lr8) * 1024
                       + t2 * 64 + scb;
      u16* d = lds + (kb2 * 2 + h) * 8192 + s * 4096 + wid * 512;
      gload16(g, d);
    }
  };
  auto stageB = [&](int h, int t2) {
    const int kb2 = t2 & 1;
    #pragma unroll
    for (int s = 0; s < 2; ++s) {
      const u16* g = Wp + (size_t)(bx * 256 + h * 128 + s * 64 + wid * 8 + lr8) * 1024
                        + t2 * 64 + scb;
      u16* d = lds + 32768 + (kb2 * 2 + h) * 8192 + s * 4096 + wid * 512;
      gload16(g, d);
    }
  };

  KLOOP_PROLOGUE()
  KLOOP_BODY(16)

  #pragma unroll
  for (int mi = 0; mi < 8; ++mi) {
    const int mbase = by * 256 + wr * 128 + mi * 16 + lg * 4;
    #pragma unroll
    for (int ni = 0; ni < 4; ++ni) {
      const int j = bx * 256 + wc * 64 + ni * 16 + li;
      f32x4 a = acc[mi][ni];
      const int sec = j >> 10, jj = j & 1023;
      const int h = jj >> 6, dd = jj & 63;
      u16* base = outp + (size_t)sec * 4194304;
      if (sec == 0) {
        #pragma unroll
        for (int rb = 0; rb < 4; ++rb) {
          const int m = mbase + rb;
          const int bb = m >> 11, n = m & 2047;
          base[(((size_t)bb * 16 + h) * 2048 + n) * 64 + dd] =
              f2b(a[rb] * 0.18033688011112042f);
        }
      } else if (sec == 1) {
        #pragma unroll
        for (int rb = 0; rb < 4; ++rb) {
          const int m = mbase + rb;
          const int bb = m >> 11, n = m & 2047;
          base[(((size_t)bb * 16 + h) * 2048 + n) * 64 + (dd ^ ((n & 7) << 3))] =
              f2b(a[rb]);
        }
      } else {
        const int bb = mbase >> 11, n = mbase & 2047;
        const int ng = n & ~63, nl = n & 63;
        const int nl2 = (nl & 51) | ((nl & 4) << 1) | ((nl & 8) >> 1);
        const int col = ng | (nl2 ^ ((dd & 7) << 3));
        ushort4 pk;
        pk.x = f2b(a[0]); pk.y = f2b(a[1]); pk.z = f2b(a[2]); pk.w = f2b(a[3]);
        *(ushort4*)&base[(((size_t)bb * 16 + h) * 64 + dd) * 2048 + col] = pk;
      }
    }
  }
}

// ---------------------------------------------------------------------------
// Flash attention, swapped-operand 32x32 MFMA, STATIC-SHIFT softmax.
// 4-buffer staging (64KB LDS), 3-ahead prefetch, steady vmcnt(8) (2 stages in
// flight across barriers); jt=0 wait fixed to cover tile-0 (race fix).
// ---------------------------------------------------------------------------
__global__ __launch_bounds__(256, 2) void attn_fwd(
    const u16* __restrict__ Q, const u16* __restrict__ K,
    const u16* __restrict__ Vt, u16* __restrict__ Out) {
  __shared__ u16 smem[4][8192];
  const int tid = threadIdx.x;
  const int l = tid & 63, w = tid >> 6;
  const int lo = l & 31, hi = l >> 5, l7 = l & 7;
  const int bh = blockIdx.x & 31, qt = blockIdx.x >> 5;
  const int b_ = bh >> 4, h = bh & 15;

  const u16* Qg = Q + ((size_t)bh * 2048 + qt * 128 + w * 32 + lo) * 64;
  const u16* Kg = K + (size_t)bh * 2048 * 64;
  const u16* Vg = Vt + (size_t)bh * 64 * 2048;

  bf16x8 qf[4];
  #pragma unroll
  for (int d = 0; d < 4; ++d) qf[d] = *(const bf16x8*)&Qg[d * 16 + hi * 8];

  f32x16 o0 = {}, o1 = {};
  float lrow = 0.f;

  auto stage = [&](int buf, int jt) {
    #pragma unroll
    for (int i = 0; i < 2; ++i)
      gload16(Kg + (size_t)jt * 4096 + i * 2048 + tid * 8,
              &smem[buf][i * 2048 + w * 512]);
    #pragma unroll
    for (int i = 0; i < 2; ++i)
      gload16(Vg + (size_t)(w * 8 + (l >> 3) + i * 32) * 2048 + jt * 64 + l7 * 8,
              &smem[buf][4096 + i * 2048 + w * 512]);
  };

  // pinned VMEM issue order: Q(4), s0(4), s1(4), s2(4)
  __builtin_amdgcn_sched_barrier(0);
  stage(0, 0);
  __builtin_amdgcn_sched_barrier(0);
  stage(1, 1);
  __builtin_amdgcn_sched_barrier(0);
  stage(2, 2);
  __builtin_amdgcn_sched_barrier(0);

  for (int jt = 0; jt < 32; ++jt) {
    // steady state: 2 newest stages may remain in flight.
    // jt=0: issued Q+s0+s1+s2=16; vmcnt(8) retires Q and s0 (tile-0 ready).
    if (jt < 30)       asm volatile("s_waitcnt vmcnt(8)" ::: "memory");
    else if (jt == 30) asm volatile("s_waitcnt vmcnt(4)" ::: "memory");
    else               asm volatile("s_waitcnt vmcnt(0)" ::: "memory");
    __builtin_amdgcn_s_barrier();
    __builtin_amdgcn_sched_barrier(0);
    if (jt + 3 < 32) stage((jt + 3) & 3, jt + 3);

    const u16* Kl = &smem[jt & 3][0];
    const u16* Vl = &smem[jt & 3][4096];

    bf16x8 kf[4][2], vf0[4], vf1[4];
    #pragma unroll
    for (int dc = 0; dc < 4; ++dc) {
      const int col = (dc * 16 + hi * 8) ^ (l7 << 3);
      kf[dc][0] = *(const bf16x8*)&Kl[lo * 64 + col];
      kf[dc][1] = *(const bf16x8*)&Kl[(32 + lo) * 64 + col];
      vf0[dc]   = *(const bf16x8*)&Vl[lo * 64 + col];
      vf1[dc]   = *(const bf16x8*)&Vl[(32 + lo) * 64 + col];
    }

    f32x16 st[2] = {};
    __builtin_amdgcn_s_setprio(1);
    #pragma unroll
    for (int dc = 0; dc < 4; ++dc) {
      st[0] = __builtin_amdgcn_mfma_f32_32x32x16_bf16(kf[dc][0], qf[dc], st[0], 0, 0, 0);
      st[1] = __builtin_amdgcn_mfma_f32_32x32x16_bf16(kf[dc][1], qf[dc], st[1], 0, 0, 0);
    }
    __builtin_amdgcn_s_setprio(0);

    // P = 2^(st - 8): no max tracking, no rescale (logits bounded)
    float p[32], sm[16];
    #pragma unroll
    for (int r = 0; r < 16; ++r) p[r]      = exp2_raw(st[0][r] - 8.f);
    #pragma unroll
    for (int r = 0; r < 16; ++r) p[16 + r] = exp2_raw(st[1][r] - 8.f);
    #pragma unroll
    for (int r = 0; r < 16; ++r) sm[r] = p[r] + p[16 + r];
    #pragma unroll
    for (int s2 = 8; s2 >= 1; s2 >>= 1)
      #pragma unroll
      for (int r = 0; r < s2; ++r) sm[r] += sm[r + s2];
    lrow += sm[0] + __shfl_xor(sm[0], 32);

    // pack P -> B-fragments (order matches V key-bitswap storage)
    bf16x8 pf[4];
    #pragma unroll
    for (int kp = 0; kp < 4; ++kp) {
      u32x4 wv;
      #pragma unroll
      for (int t2 = 0; t2 < 4; ++t2)
        wv[t2] = cvtpk(p[(kp >> 1) * 16 + (kp & 1) * 8 + t2 * 2],
                       p[(kp >> 1) * 16 + (kp & 1) * 8 + t2 * 2 + 1]);
      union { u32x4 a; bf16x8 b; } cc; cc.a = wv;
      pf[kp] = cc.b;
    }

    __builtin_amdgcn_s_setprio(1);
    #pragma unroll
    for (int kp = 0; kp < 4; ++kp) {
      o0 = __builtin_amdgcn_mfma_f32_32x32x16_bf16(vf0[kp], pf[kp], o0, 0, 0, 0);
      o1 = __builtin_amdgcn_mfma_f32_32x32x16_bf16(vf1[kp], pf[kp], o1, 0, 0, 0);
    }
    __builtin_amdgcn_s_setprio(0);
  }

  const float inv = 1.f / lrow;
  u16* Ob = Out + ((size_t)b_ * 2048 + qt * 128 + w * 32 + lo) * 1024 + h * 64;
  #pragma unroll
  for (int dd = 0; dd < 2; ++dd) {
    #pragma unroll
    for (int R = 0; R < 4; ++R) {
      ushort4 pk;
      const f32x16 oo = dd ? o1 : o0;
      pk.x = f2b(oo[4 * R + 0] * inv); pk.y = f2b(oo[4 * R + 1] * inv);
      pk.z = f2b(oo[4 * R + 2] * inv); pk.w = f2b(oo[4 * R + 3] * inv);
      *(ushort4*)&Ob[dd * 32 + 8 * R + 4 * hi] = pk;
    }
  }
}

// ---------------------------------------------------------------------------
// Host launch
// ---------------------------------------------------------------------------
extern "C" void kernel_launch(void* const* d_in, const int* in_sizes, int n_in,
                              void* d_out, int out_size, void* d_ws, size_t ws_size,
                              hipStream_t stream) {
  const float* x    = (const float*)d_in[0];
  const float* ln1g = (const float*)d_in[1];
  const float* ln1b = (const float*)d_in[2];
  const float* wq1  = (const float*)d_in[3];
  const float* wk1  = (const float*)d_in[4];
  const float* wv1  = (const float*)d_in[5];
  const float* wo1  = (const float*)d_in[6];
  const float* bo1  = (const float*)d_in[7];
  const float* ln2g = (const float*)d_in[8];
  const float* ln2b = (const float*)d_in[9];
  const float* wq2  = (const float*)d_in[10];
  const float* wk2  = (const float*)d_in[11];
  const float* wv2  = (const float*)d_in[12];
  const float* wo2  = (const float*)d_in[13];
  const float* bo2  = (const float*)d_in[14];
  const float* ln3g = (const float*)d_in[15];
  const float* ln3b = (const float*)d_in[16];
  const float* wff1 = (const float*)d_in[17];
  const float* bff1 = (const float*)d_in[18];
  const float* wff2 = (const float*)d_in[19];
  const float* bff2 = (const float*)d_in[20];

  char* ws = (char*)d_ws;
  const size_t MB = 1024 * 1024;
  u16* wqkv1b = (u16*)(ws + 0 * MB);
  u16* wo1b   = (u16*)(ws + 6 * MB);
  u16* wqkv2b = (u16*)(ws + 8 * MB);
  u16* wo2b   = (u16*)(ws + 14 * MB);
  u16* wff1p  = (u16*)(ws + 16 * MB);
  u16* wff2b  = (u16*)(ws + 32 * MB);
  u16* xn     = (u16*)(ws + 40 * MB);
  u16* Qb     = (u16*)(ws + 48 * MB);
  float* x1   = (float*)(ws + 72 * MB);
  float* x2   = (float*)(ws + 88 * MB);
  u16* hact   = (u16*)(ws + 48 * MB);
  u16* Kb  = Qb + 4194304;
  u16* Vtb = Qb + 8388608;

  hipFuncSetAttribute((const void*)gemm_ff1,
                      hipFuncAttributeMaxDynamicSharedMemorySize, 131072);
  hipFuncSetAttribute((const void*)gemm_qkv,
                      hipFuncAttributeMaxDynamicSharedMemorySize, 131072);
  hipFuncSetAttribute((const void*)gemm_out,
                      hipFuncAttributeMaxDynamicSharedMemorySize, 65536);

  castall<<<20480, 256, 0, stream>>>(wq1, wk1, wv1, wo1, wq2, wk2, wv2, wo2,
                                     wff1, wff2,
                                     wqkv1b, wo1b, wqkv2b, wo2b, wff1p, wff2b);

  // ---- attention block 1 ----
  ln_kernel<<<4096, 256, 0, stream>>>(x, ln1g, ln1b, xn);
  gemm_qkv<<<192, 512, 131072, stream>>>(xn, wqkv1b, Qb);
  attn_fwd<<<512, 256, 0, stream>>>(Qb, Kb, Vtb, xn);
  gemm_out<<<256, 512, 65536, stream>>>(xn, wo1b, bo1, x, x1, 1024, 1024);

  // ---- attention block 2 ----
  ln_kernel<<<4096, 256, 0, stream>>>(x1, ln2g, ln2b, xn);
  gemm_qkv<<<192, 512, 131072, stream>>>(xn, wqkv2b, Qb);
  attn_fwd<<<512, 256, 0, stream>>>(Qb, Kb, Vtb, xn);
  gemm_out<<<256, 512, 65536, stream>>>(xn, wo2b, bo2, x1, x2, 1024, 1024);

  // ---- GEGLU FF ----
  ln_kernel<<<4096, 256, 0, stream>>>(x2, ln3g, ln3b, xn);
  gemm_ff1<<<512, 512, 131072, stream>>>(xn, wff1p, bff1, hact);
  gemm_out<<<256, 512, 65536, stream>>>(hact, wff2b, bff2, x2, (float*)d_out, 1024, 4096);
}

// Round 13
// 359.876 us; speedup vs baseline: 1.1733x; 1.0020x over previous
//
#include <hip/hip_runtime.h>
#include <hip/hip_bf16.h>

using bf16x8 = __attribute__((ext_vector_type(8))) short;
using f32x4  = __attribute__((ext_vector_type(4))) float;
using f32x16 = __attribute__((ext_vector_type(16))) float;
typedef unsigned int u32;
typedef unsigned short u16;
using u32x4 = __attribute__((ext_vector_type(4))) u32;

__device__ __forceinline__ u16 f2b(float f) {
  union { float f; u32 u; } v; v.f = f;
  return (u16)((v.u + 0x7FFFu + ((v.u >> 16) & 1u)) >> 16);
}

__device__ __forceinline__ u32 cvtpk(float lo, float hi) {
  u32 r;
  asm("v_cvt_pk_bf16_f32 %0, %1, %2" : "=v"(r) : "v"(lo), "v"(hi));
  return r;
}

__device__ __forceinline__ float exp2_raw(float x) {
  float r;
  asm("v_exp_f32 %0, %1" : "=v"(r) : "v"(x));
  return r;
}

__device__ __forceinline__ void gload16(const void* g, void* l) {
  __builtin_amdgcn_global_load_lds((const __attribute__((address_space(1))) u32*)g,
                                   (__attribute__((address_space(3))) u32*)l, 16, 0, 0);
}

// gelu via tanh approx: x * u/(u+1), u = 2^(2*0.79788456*log2e*(x+0.044715x^3))
__device__ __forceinline__ float gelu_fast(float x) {
  const float x2 = x * x;
  const float t = x * fmaf(0.044715f, x2, 1.f);
  const float u = exp2f(2.3022080f * t);
  return x * u * __builtin_amdgcn_rcpf(u + 1.f);
}

// ---------------------------------------------------------------------------
// Fused weight cast fp32 -> bf16 (QKV packed; FF1 a/gate interleaved per 16)
// ---------------------------------------------------------------------------
__global__ __launch_bounds__(256) void castall(
    const float* __restrict__ wq1, const float* __restrict__ wk1,
    const float* __restrict__ wv1, const float* __restrict__ wo1,
    const float* __restrict__ wq2, const float* __restrict__ wk2,
    const float* __restrict__ wv2, const float* __restrict__ wo2,
    const float* __restrict__ wff1, const float* __restrict__ wff2,
    u16* __restrict__ qkv1, u16* __restrict__ o1,
    u16* __restrict__ qkv2, u16* __restrict__ o2,
    u16* __restrict__ ff1p, u16* __restrict__ ff2) {
  const long e = ((long)blockIdx.x * 256 + threadIdx.x) * 4;
  constexpr long M1 = 1l << 20;
  const float* s; u16* d;
  if (e < 3 * M1) {
    s = (e < M1 ? wq1 + e : (e < 2 * M1 ? wk1 + (e - M1) : wv1 + (e - 2 * M1)));
    d = qkv1 + e;
  } else if (e < 4 * M1) {
    s = wo1 + (e - 3 * M1); d = o1 + (e - 3 * M1);
  } else if (e < 7 * M1) {
    long r = e - 4 * M1;
    s = (r < M1 ? wq2 + r : (r < 2 * M1 ? wk2 + (r - M1) : wv2 + (r - 2 * M1)));
    d = qkv2 + r;
  } else if (e < 8 * M1) {
    s = wo2 + (e - 7 * M1); d = o2 + (e - 7 * M1);
  } else if (e < 16 * M1) {
    long r = e - 8 * M1;
    long p = r >> 10, col = r & 1023;
    long g = p >> 5, rr = p & 31;
    long lr = (rr < 16) ? (g << 4) + rr : 4096 + (g << 4) + (rr - 16);
    s = wff1 + (lr << 10) + col; d = ff1p + r;
  } else {
    long r = e - 16 * M1;
    s = wff2 + r; d = ff2 + r;
  }
  float4 v = *(const float4*)s;
  ushort4 o;
  o.x = f2b(v.x); o.y = f2b(v.y); o.z = f2b(v.z); o.w = f2b(v.w);
  *(ushort4*)d = o;
}

// ---------------------------------------------------------------------------
// LayerNorm: one block per row of 1024, fp32 in -> bf16 out
// ---------------------------------------------------------------------------
__global__ __launch_bounds__(256) void ln_kernel(const float* __restrict__ x,
                                                 const float* __restrict__ g,
                                                 const float* __restrict__ b,
                                                 u16* __restrict__ y) {
  const int row = blockIdx.x;
  const int t = threadIdx.x;
  const float* xr = x + (size_t)row * 1024;
  float4 v = ((const float4*)xr)[t];
  float s  = v.x + v.y + v.z + v.w;
  float s2 = v.x * v.x + v.y * v.y + v.z * v.z + v.w * v.w;
  #pragma unroll
  for (int m = 1; m < 64; m <<= 1) {
    s  += __shfl_xor(s, m);
    s2 += __shfl_xor(s2, m);
  }
  __shared__ float red[8];
  if ((t & 63) == 0) { red[(t >> 6) * 2] = s; red[(t >> 6) * 2 + 1] = s2; }
  __syncthreads();
  s  = red[0] + red[2] + red[4] + red[6];
  s2 = red[1] + red[3] + red[5] + red[7];
  const float mu = s * (1.f / 1024.f);
  const float var = s2 * (1.f / 1024.f) - mu * mu;
  const float rs = rsqrtf(var + 1e-5f);
  float4 gv = ((const float4*)g)[t];
  float4 bv = ((const float4*)b)[t];
  ushort4 o;
  o.x = f2b((v.x - mu) * rs * gv.x + bv.x);
  o.y = f2b((v.y - mu) * rs * gv.y + bv.y);
  o.z = f2b((v.z - mu) * rs * gv.z + bv.z);
  o.w = f2b((v.w - mu) * rs * gv.w + bv.w);
  ((ushort4*)(y + (size_t)row * 1024))[t] = o;
}

// ---------------------------------------------------------------------------
// gemm_out: C[M,N] = A[M,K] @ Bw[N,K]^T, fp32 out = acc + bias + resid.
// 128x128 tile, 8 waves, BK=64, dbuf, XOR swizzle, counted vmcnt, setprio.
// ---------------------------------------------------------------------------
__global__ __launch_bounds__(512, 4) void gemm_out(
    const u16* __restrict__ A, const u16* __restrict__ Bw,
    const float* __restrict__ bias, const float* __restrict__ resid,
    float* __restrict__ out, int N, int K) {
  extern __shared__ u16 lds[];
  const int tid = threadIdx.x;
  const int l = tid & 63, wid = tid >> 6;
  const int li = l & 15, lg = l >> 4;
  const int wr = wid >> 2, wc = wid & 3;
  const int nx = N >> 7;
  const int cpx = gridDim.x >> 3;
  const int v = (blockIdx.x & 7) * cpx + (blockIdx.x >> 3);
  const int by = v / nx, bx = v - by * nx;
  const int m0 = by << 7, n0 = bx << 7;

  const int sr = tid >> 3;
  const int sc = ((tid & 7) ^ (sr & 7)) << 3;
  const int dc = (tid & 7) << 3;
  const int sc0 = (lg * 8) ^ ((li & 7) << 3);
  const int sc1 = sc0 ^ 32;

  f32x4 acc[4][2] = {};

  auto stageA = [&](int kb, int t2) {
    #pragma unroll
    for (int s = 0; s < 2; ++s)
      gload16(A + (size_t)(m0 + s * 64 + sr) * K + t2 * 64 + sc,
              lds + kb * 8192 + (s * 64 + sr) * 64 + dc);
  };
  auto stageB = [&](int kb, int t2) {
    #pragma unroll
    for (int s = 0; s < 2; ++s)
      gload16(Bw + (size_t)(n0 + s * 64 + sr) * K + t2 * 64 + sc,
              lds + 16384 + kb * 8192 + (s * 64 + sr) * 64 + dc);
  };

  const int NT = K >> 6;
  stageA(0, 0); stageB(0, 0);
  __builtin_amdgcn_sched_barrier(0);
  stageA(1, 1); stageB(1, 1);
  __builtin_amdgcn_sched_barrier(0);
  asm volatile("s_waitcnt vmcnt(4)" ::: "memory");
  __builtin_amdgcn_s_barrier();
  __builtin_amdgcn_sched_barrier(0);

  for (int t = 0; t < NT; ++t) {
    const int kb = t & 1;
    const u16* Ab = lds + kb * 8192 + (wr * 64 + li) * 64;
    const u16* Bb = lds + 16384 + kb * 8192 + (wc * 32 + li) * 64;
    bf16x8 a[4], b[2];

    #pragma unroll
    for (int mi = 0; mi < 4; ++mi) a[mi] = *(const bf16x8*)(Ab + mi * 1024 + sc0);
    #pragma unroll
    for (int n = 0; n < 2; ++n)  b[n]  = *(const bf16x8*)(Bb + n * 1024 + sc0);
    __builtin_amdgcn_s_barrier();
    __builtin_amdgcn_s_setprio(1);
    #pragma unroll
    for (int mi = 0; mi < 4; ++mi)
      #pragma unroll
      for (int n = 0; n < 2; ++n)
        acc[mi][n] = __builtin_amdgcn_mfma_f32_16x16x32_bf16(a[mi], b[n], acc[mi][n], 0, 0, 0);
    __builtin_amdgcn_s_setprio(0);
    __builtin_amdgcn_s_barrier();

    #pragma unroll
    for (int mi = 0; mi < 4; ++mi) a[mi] = *(const bf16x8*)(Ab + mi * 1024 + sc1);
    #pragma unroll
    for (int n = 0; n < 2; ++n)  b[n]  = *(const bf16x8*)(Bb + n * 1024 + sc1);
    __builtin_amdgcn_s_barrier();
    __builtin_amdgcn_s_setprio(1);
    #pragma unroll
    for (int mi = 0; mi < 4; ++mi)
      #pragma unroll
      for (int n = 0; n < 2; ++n)
        acc[mi][n] = __builtin_amdgcn_mfma_f32_16x16x32_bf16(a[mi], b[n], acc[mi][n], 0, 0, 0);
    __builtin_amdgcn_s_setprio(0);
    if (t + 2 < NT) {
      stageA(kb, t + 2); stageB(kb, t + 2);
      asm volatile("s_waitcnt vmcnt(4)" ::: "memory");
    } else if (t + 2 == NT) {
      asm volatile("s_waitcnt vmcnt(0)" ::: "memory");
    }
    __builtin_amdgcn_s_barrier();
    __builtin_amdgcn_sched_barrier(0);
  }

  #pragma unroll
  for (int mi = 0; mi < 4; ++mi) {
    const int m = m0 + wr * 64 + mi * 16 + lg * 4;
    #pragma unroll
    for (int n = 0; n < 2; ++n) {
      const int j = n0 + wc * 32 + n * 16 + li;
      const float bj = bias[j];
      #pragma unroll
      for (int rb = 0; rb < 4; ++rb)
        out[(size_t)(m + rb) * N + j] =
            acc[mi][n][rb] + bj + resid[(size_t)(m + rb) * N + j];
    }
  }
}

// ===========================================================================
// 256x256 4-phase K-loop, ONE barrier per phase (4/tile).
// ===========================================================================
#define KLOOP_PROLOGUE()                                                      \
  stageA(0, 0); stageB(0, 0); stageA(1, 0); stageB(1, 0);                     \
  __builtin_amdgcn_sched_barrier(0);                                          \
  stageA(0, 1); stageB(0, 1);                                                 \
  __builtin_amdgcn_sched_barrier(0);                                          \
  asm volatile("s_waitcnt vmcnt(4)" ::: "memory");                            \
  __builtin_amdgcn_s_barrier();                                               \
  __builtin_amdgcn_sched_barrier(0);

#define KLOOP_BODY(NT)                                                        \
  bf16x8 b0[4], b1[4];                                                        \
  for (int t = 0; t < NT; ++t) {                                              \
    const int kb = t & 1;                                                     \
    const u16* Abase0 = lds + (kb * 2 + 0) * 8192 + rowA0;                    \
    const u16* Abase1 = lds + (kb * 2 + 1) * 8192 + rowA0;                    \
    const u16* Bbase  = lds + (kb * 2 + bhn) * 8192 + rowB0;                  \
    bf16x8 a[4];                                                              \
    /* phase 1: (qm0, k0) */                                                  \
    _Pragma("unroll")                                                         \
    for (int j = 0; j < 4; ++j) a[j]  = *(const bf16x8*)(Abase0 + j * 1024 + sc0); \
    _Pragma("unroll")                                                         \
    for (int n = 0; n < 4; ++n) b0[n] = *(const bf16x8*)(Bbase + n * 1024 + sc0); \
    if (t + 1 < NT) stageA(1, t + 1);                                         \
    __builtin_amdgcn_s_setprio(1);                                            \
    _Pragma("unroll")                                                         \
    for (int j = 0; j < 4; ++j)                                               \
      _Pragma("unroll")                                                       \
      for (int n = 0; n < 4; ++n)                                             \
        acc[j][n] = __builtin_amdgcn_mfma_f32_16x16x32_bf16(a[j], b0[n], acc[j][n], 0, 0, 0); \
    __builtin_amdgcn_s_setprio(0);                                            \
    __builtin_amdgcn_s_barrier();                                             \
    /* phase 2: (qm0, k1) */                                                  \
    _Pragma("unroll")                                                         \
    for (int j = 0; j < 4; ++j) a[j]  = *(const bf16x8*)(Abase0 + j * 1024 + sc1); \
    _Pragma("unroll")                                                         \
    for (int n = 0; n < 4; ++n) b1[n] = *(const bf16x8*)(Bbase + n * 1024 + sc1); \
    if (t + 1 < NT) stageB(1, t + 1);                                         \
    __builtin_amdgcn_s_setprio(1);                                            \
    _Pragma("unroll")                                                         \
    for (int j = 0; j < 4; ++j)                                               \
      _Pragma("unroll")                                                       \
      for (int n = 0; n < 4; ++n)                                             \
        acc[j][n] = __builtin_amdgcn_mfma_f32_16x16x32_bf16(a[j], b1[n], acc[j][n], 0, 0, 0); \
    __builtin_amdgcn_s_setprio(0);                                            \
    __builtin_amdgcn_s_barrier();                                             \
    /* phase 3: (qm1, k0) */                                                  \
    _Pragma("unroll")                                                         \
    for (int j = 0; j < 4; ++j) a[j] = *(const bf16x8*)(Abase1 + j * 1024 + sc0); \
    if (t + 2 < NT) stageA(0, t + 2);                                         \
    __builtin_amdgcn_s_setprio(1);                                            \
    _Pragma("unroll")                                                         \
    for (int j = 0; j < 4; ++j)                                               \
      _Pragma("unroll")                                                       \
      for (int n = 0; n < 4; ++n)                                             \
        acc[4 + j][n] = __builtin_amdgcn_mfma_f32_16x16x32_bf16(a[j], b0[n], acc[4 + j][n], 0, 0, 0); \
    __builtin_amdgcn_s_setprio(0);                                            \
    __builtin_amdgcn_s_barrier();                                             \
    /* phase 4: (qm1, k1) */                                                  \
    _Pragma("unroll")                                                         \
    for (int j = 0; j < 4; ++j) a[j] = *(const bf16x8*)(Abase1 + j * 1024 + sc1); \
    if (t + 2 < NT) stageB(0, t + 2);                                         \
    __builtin_amdgcn_s_setprio(1);                                            \
    _Pragma("unroll")                                                         \
    for (int j = 0; j < 4; ++j)                                               \
      _Pragma("unroll")                                                       \
      for (int n = 0; n < 4; ++n)                                             \
        acc[4 + j][n] = __builtin_amdgcn_mfma_f32_16x16x32_bf16(a[j], b1[n], acc[4 + j][n], 0, 0, 0); \
    __builtin_amdgcn_s_setprio(0);                                            \
    if (t < NT - 2)       asm volatile("s_waitcnt vmcnt(4)" ::: "memory");    \
    else if (t == NT - 2) asm volatile("s_waitcnt vmcnt(0)" ::: "memory");    \
    __builtin_amdgcn_s_barrier();                                             \
  }

// ---------------------------------------------------------------------------
// FF1: 256x256 packed-GEGLU GEMM. XCD decode: 8x8 2D chunk per XCD.
// ---------------------------------------------------------------------------
__global__ __launch_bounds__(512, 2) void gemm_ff1(
    const u16* __restrict__ A, const u16* __restrict__ Wp,
    const float* __restrict__ bias, u16* __restrict__ out) {
  extern __shared__ u16 lds[];
  const int tid = threadIdx.x;
  const int l = tid & 63, wid = tid >> 6;
  const int li = l & 15, lg = l >> 4;
  const int wr = wid >> 2, wc = wid & 3;
  const int xcd = blockIdx.x & 7, r = blockIdx.x >> 3;   // r in [0,64)
  const int bx = (xcd & 3) * 8 + (r >> 3);               // [0,32)
  const int by = (xcd >> 2) * 8 + (r & 7);               // [0,16)

  const int lr8 = l >> 3;
  const int scb = ((l & 7) ^ lr8) << 3;
  const int sc0 = (lg * 8) ^ ((li & 7) << 3);
  const int sc1 = sc0 ^ 32;

  const int rowA0 = (wr * 64 + li) * 64;
  const int rowB0 = 32768 + ((wc & 1) * 64 + li) * 64;
  const int bhn = wc >> 1;

  f32x4 acc[8][4] = {};

  auto stageA = [&](int h, int t2) {
    const int kb2 = t2 & 1;
    #pragma unroll
    for (int s = 0; s < 2; ++s) {
      const u16* g = A + (size_t)(by * 256 + s * 128 + h * 64 + wid * 8 + lr8) * 1024
                       + t2 * 64 + scb;
      u16* d = lds + (kb2 * 2 + h) * 8192 + s * 4096 + wid * 512;
      gload16(g, d);
    }
  };
  auto stageB = [&](int h, int t2) {
    const int kb2 = t2 & 1;
    #pragma unroll
    for (int s = 0; s < 2; ++s) {
      const u16* g = Wp + (size_t)(bx * 256 + h * 128 + s * 64 + wid * 8 + lr8) * 1024
                        + t2 * 64 + scb;
      u16* d = lds + 32768 + (kb2 * 2 + h) * 8192 + s * 4096 + wid * 512;
      gload16(g, d);
    }
  };

  KLOOP_PROLOGUE()
  KLOOP_BODY(16)

  #pragma unroll
  for (int nj = 0; nj < 2; ++nj) {
    const int c = bx * 128 + wc * 32 + nj * 16 + li;
    const float ba = bias[c];
    const float bg = bias[4096 + c];
    #pragma unroll
    for (int mi = 0; mi < 8; ++mi) {
      #pragma unroll
      for (int rb = 0; rb < 4; ++rb) {
        const float av = acc[mi][2 * nj][rb] + ba;
        const float gv = acc[mi][2 * nj + 1][rb] + bg;
        out[(size_t)(by * 256 + wr * 128 + mi * 16 + lg * 4 + rb) * 4096 + c]
            = f2b(av * gelu_fast(gv));
      }
    }
  }
}

// ---------------------------------------------------------------------------
// QKV: 256x256 4-phase GEMM, N=3072. XCD decode: 4by x 6bx chunk per XCD.
// ---------------------------------------------------------------------------
__global__ __launch_bounds__(512, 2) void gemm_qkv(
    const u16* __restrict__ A, const u16* __restrict__ Wp,
    u16* __restrict__ outp) {
  extern __shared__ u16 lds[];
  const int tid = threadIdx.x;
  const int l = tid & 63, wid = tid >> 6;
  const int li = l & 15, lg = l >> 4;
  const int wr = wid >> 2, wc = wid & 3;
  const int xcd = blockIdx.x & 7, r = blockIdx.x >> 3;   // r in [0,24)
  const int by = (xcd >> 1) * 4 + r / 6;                 // [0,16)
  const int bx = (xcd & 1) * 6 + r % 6;                  // [0,12)

  const int lr8 = l >> 3;
  const int scb = ((l & 7) ^ lr8) << 3;
  const int sc0 = (lg * 8) ^ ((li & 7) << 3);
  const int sc1 = sc0 ^ 32;

  const int rowA0 = (wr * 64 + li) * 64;
  const int rowB0 = 32768 + ((wc & 1) * 64 + li) * 64;
  const int bhn = wc >> 1;

  f32x4 acc[8][4] = {};

  auto stageA = [&](int h, int t2) {
    const int kb2 = t2 & 1;
    #pragma unroll
    for (int s = 0; s < 2; ++s) {
      const u16* g = A + (size_t)(by * 256 + s * 128 + h * 64 + wid * 8 + lr8) * 1024
                       + t2 * 64 + scb;
      u16* d = lds + (kb2 * 2 + h) * 8192 + s * 4096 + wid * 512;
      gload16(g, d);
    }
  };
  auto stageB = [&](int h, int t2) {
    const int kb2 = t2 & 1;
    #pragma unroll
    for (int s = 0; s < 2; ++s) {
      const u16* g = Wp + (size_t)(bx * 256 + h * 128 + s * 64 + wid * 8 + lr8) * 1024
                        + t2 * 64 + scb;
      u16* d = lds + 32768 + (kb2 * 2 + h) * 8192 + s * 4096 + wid * 512;
      gload16(g, d);
    }
  };

  KLOOP_PROLOGUE()
  KLOOP_BODY(16)

  #pragma unroll
  for (int mi = 0; mi < 8; ++mi) {
    const int mbase = by * 256 + wr * 128 + mi * 16 + lg * 4;
    #pragma unroll
    for (int ni = 0; ni < 4; ++ni) {
      const int j = bx * 256 + wc * 64 + ni * 16 + li;
      f32x4 a = acc[mi][ni];
      const int sec = j >> 10, jj = j & 1023;
      const int h = jj >> 6, dd = jj & 63;
      u16* base = outp + (size_t)sec * 4194304;
      if (sec == 0) {
        #pragma unroll
        for (int rb = 0; rb < 4; ++rb) {
          const int m = mbase + rb;
          const int bb = m >> 11, n = m & 2047;
          base[(((size_t)bb * 16 + h) * 2048 + n) * 64 + dd] =
              f2b(a[rb] * 0.18033688011112042f);
        }
      } else if (sec == 1) {
        #pragma unroll
        for (int rb = 0; rb < 4; ++rb) {
          const int m = mbase + rb;
          const int bb = m >> 11, n = m & 2047;
          base[(((size_t)bb * 16 + h) * 2048 + n) * 64 + (dd ^ ((n & 7) << 3))] =
              f2b(a[rb]);
        }
      } else {
        const int bb = mbase >> 11, n = mbase & 2047;
        const int ng = n & ~63, nl = n & 63;
        const int nl2 = (nl & 51) | ((nl & 4) << 1) | ((nl & 8) >> 1);
        const int col = ng | (nl2 ^ ((dd & 7) << 3));
        ushort4 pk;
        pk.x = f2b(a[0]); pk.y = f2b(a[1]); pk.z = f2b(a[2]); pk.w = f2b(a[3]);
        *(ushort4*)&base[(((size_t)bb * 16 + h) * 64 + dd) * 2048 + col] = pk;
      }
    }
  }
}

// ---------------------------------------------------------------------------
// Flash attention, swapped-operand 32x32 MFMA, STATIC-SHIFT softmax.
// Row-sum computed on the MFMA pipe: lacc = sum_kp mfma(ones, pf[kp], lacc)
// accumulated across tiles (valid because no per-tile rescale). Removes the
// serial 31-op VALU sum tree + shuffle from every tile.
// 4-buffer staging, 3-ahead prefetch, steady vmcnt(8).
// ---------------------------------------------------------------------------
__global__ __launch_bounds__(256, 2) void attn_fwd(
    const u16* __restrict__ Q, const u16* __restrict__ K,
    const u16* __restrict__ Vt, u16* __restrict__ Out) {
  __shared__ u16 smem[4][8192];
  const int tid = threadIdx.x;
  const int l = tid & 63, w = tid >> 6;
  const int lo = l & 31, hi = l >> 5, l7 = l & 7;
  const int bh = blockIdx.x & 31, qt = blockIdx.x >> 5;
  const int b_ = bh >> 4, h = bh & 15;

  const u16* Qg = Q + ((size_t)bh * 2048 + qt * 128 + w * 32 + lo) * 64;
  const u16* Kg = K + (size_t)bh * 2048 * 64;
  const u16* Vg = Vt + (size_t)bh * 64 * 2048;

  bf16x8 qf[4];
  #pragma unroll
  for (int d = 0; d < 4; ++d) qf[d] = *(const bf16x8*)&Qg[d * 16 + hi * 8];

  const bf16x8 onesf = {(short)0x3F80, (short)0x3F80, (short)0x3F80, (short)0x3F80,
                        (short)0x3F80, (short)0x3F80, (short)0x3F80, (short)0x3F80};

  f32x16 o0 = {}, o1 = {}, lacc = {};

  auto stage = [&](int buf, int jt) {
    #pragma unroll
    for (int i = 0; i < 2; ++i)
      gload16(Kg + (size_t)jt * 4096 + i * 2048 + tid * 8,
              &smem[buf][i * 2048 + w * 512]);
    #pragma unroll
    for (int i = 0; i < 2; ++i)
      gload16(Vg + (size_t)(w * 8 + (l >> 3) + i * 32) * 2048 + jt * 64 + l7 * 8,
              &smem[buf][4096 + i * 2048 + w * 512]);
  };

  // pinned VMEM issue order: Q(4), s0(4), s1(4), s2(4)
  __builtin_amdgcn_sched_barrier(0);
  stage(0, 0);
  __builtin_amdgcn_sched_barrier(0);
  stage(1, 1);
  __builtin_amdgcn_sched_barrier(0);
  stage(2, 2);
  __builtin_amdgcn_sched_barrier(0);

  for (int jt = 0; jt < 32; ++jt) {
    if (jt < 30)       asm volatile("s_waitcnt vmcnt(8)" ::: "memory");
    else if (jt == 30) asm volatile("s_waitcnt vmcnt(4)" ::: "memory");
    else               asm volatile("s_waitcnt vmcnt(0)" ::: "memory");
    __builtin_amdgcn_s_barrier();
    __builtin_amdgcn_sched_barrier(0);
    if (jt + 3 < 32) stage((jt + 3) & 3, jt + 3);

    const u16* Kl = &smem[jt & 3][0];
    const u16* Vl = &smem[jt & 3][4096];

    bf16x8 kf[4][2], vf0[4], vf1[4];
    #pragma unroll
    for (int dc = 0; dc < 4; ++dc) {
      const int col = (dc * 16 + hi * 8) ^ (l7 << 3);
      kf[dc][0] = *(const bf16x8*)&Kl[lo * 64 + col];
      kf[dc][1] = *(const bf16x8*)&Kl[(32 + lo) * 64 + col];
      vf0[dc]   = *(const bf16x8*)&Vl[lo * 64 + col];
      vf1[dc]   = *(const bf16x8*)&Vl[(32 + lo) * 64 + col];
    }

    f32x16 st[2] = {};
    __builtin_amdgcn_s_setprio(1);
    #pragma unroll
    for (int dc = 0; dc < 4; ++dc) {
      st[0] = __builtin_amdgcn_mfma_f32_32x32x16_bf16(kf[dc][0], qf[dc], st[0], 0, 0, 0);
      st[1] = __builtin_amdgcn_mfma_f32_32x32x16_bf16(kf[dc][1], qf[dc], st[1], 0, 0, 0);
    }
    __builtin_amdgcn_s_setprio(0);

    // P = 2^(st - 8): no max tracking, no rescale (logits bounded)
    float p[32];
    #pragma unroll
    for (int r = 0; r < 16; ++r) p[r]      = exp2_raw(st[0][r] - 8.f);
    #pragma unroll
    for (int r = 0; r < 16; ++r) p[16 + r] = exp2_raw(st[1][r] - 8.f);

    // pack P -> B-fragments (order matches V key-bitswap storage)
    bf16x8 pf[4];
    #pragma unroll
    for (int kp = 0; kp < 4; ++kp) {
      u32x4 wv;
      #pragma unroll
      for (int t2 = 0; t2 < 4; ++t2)
        wv[t2] = cvtpk(p[(kp >> 1) * 16 + (kp & 1) * 8 + t2 * 2],
                       p[(kp >> 1) * 16 + (kp & 1) * 8 + t2 * 2 + 1]);
      union { u32x4 a; bf16x8 b; } cc; cc.a = wv;
      pf[kp] = cc.b;
    }

    __builtin_amdgcn_s_setprio(1);
    #pragma unroll
    for (int kp = 0; kp < 4; ++kp) {
      o0   = __builtin_amdgcn_mfma_f32_32x32x16_bf16(vf0[kp], pf[kp], o0, 0, 0, 0);
      o1   = __builtin_amdgcn_mfma_f32_32x32x16_bf16(vf1[kp], pf[kp], o1, 0, 0, 0);
      lacc = __builtin_amdgcn_mfma_f32_32x32x16_bf16(onesf,   pf[kp], lacc, 0, 0, 0);
    }
    __builtin_amdgcn_s_setprio(0);
  }

  const float inv = 1.f / lacc[0];
  u16* Ob = Out + ((size_t)b_ * 2048 + qt * 128 + w * 32 + lo) * 1024 + h * 64;
  #pragma unroll
  for (int dd = 0; dd < 2; ++dd) {
    #pragma unroll
    for (int R = 0; R < 4; ++R) {
      ushort4 pk;
      const f32x16 oo = dd ? o1 : o0;
      pk.x = f2b(oo[4 * R + 0] * inv); pk.y = f2b(oo[4 * R + 1] * inv);
      pk.z = f2b(oo[4 * R + 2] * inv); pk.w = f2b(oo[4 * R + 3] * inv);
      *(ushort4*)&Ob[dd * 32 + 8 * R + 4 * hi] = pk;
    }
  }
}

// ---------------------------------------------------------------------------
// Host launch
// ---------------------------------------------------------------------------
extern "C" void kernel_launch(void* const* d_in, const int* in_sizes, int n_in,
                              void* d_out, int out_size, void* d_ws, size_t ws_size,
                              hipStream_t stream) {
  const float* x    = (const float*)d_in[0];
  const float* ln1g = (const float*)d_in[1];
  const float* ln1b = (const float*)d_in[2];
  const float* wq1  = (const float*)d_in[3];
  const float* wk1  = (const float*)d_in[4];
  const float* wv1  = (const float*)d_in[5];
  const float* wo1  = (const float*)d_in[6];
  const float* bo1  = (const float*)d_in[7];
  const float* ln2g = (const float*)d_in[8];
  const float* ln2b = (const float*)d_in[9];
  const float* wq2  = (const float*)d_in[10];
  const float* wk2  = (const float*)d_in[11];
  const float* wv2  = (const float*)d_in[12];
  const float* wo2  = (const float*)d_in[13];
  const float* bo2  = (const float*)d_in[14];
  const float* ln3g = (const float*)d_in[15];
  const float* ln3b = (const float*)d_in[16];
  const float* wff1 = (const float*)d_in[17];
  const float* bff1 = (const float*)d_in[18];
  const float* wff2 = (const float*)d_in[19];
  const float* bff2 = (const float*)d_in[20];

  char* ws = (char*)d_ws;
  const size_t MB = 1024 * 1024;
  u16* wqkv1b = (u16*)(ws + 0 * MB);
  u16* wo1b   = (u16*)(ws + 6 * MB);
  u16* wqkv2b = (u16*)(ws + 8 * MB);
  u16* wo2b   = (u16*)(ws + 14 * MB);
  u16* wff1p  = (u16*)(ws + 16 * MB);
  u16* wff2b  = (u16*)(ws + 32 * MB);
  u16* xn     = (u16*)(ws + 40 * MB);
  u16* Qb     = (u16*)(ws + 48 * MB);
  float* x1   = (float*)(ws + 72 * MB);
  float* x2   = (float*)(ws + 88 * MB);
  u16* hact   = (u16*)(ws + 48 * MB);
  u16* Kb  = Qb + 4194304;
  u16* Vtb = Qb + 8388608;

  hipFuncSetAttribute((const void*)gemm_ff1,
                      hipFuncAttributeMaxDynamicSharedMemorySize, 131072);
  hipFuncSetAttribute((const void*)gemm_qkv,
                      hipFuncAttributeMaxDynamicSharedMemorySize, 131072);
  hipFuncSetAttribute((const void*)gemm_out,
                      hipFuncAttributeMaxDynamicSharedMemorySize, 65536);

  castall<<<20480, 256, 0, stream>>>(wq1, wk1, wv1, wo1, wq2, wk2, wv2, wo2,
                                     wff1, wff2,
                                     wqkv1b, wo1b, wqkv2b, wo2b, wff1p, wff2b);

  // ---- attention block 1 ----
  ln_kernel<<<4096, 256, 0, stream>>>(x, ln1g, ln1b, xn);
  gemm_qkv<<<192, 512, 131072, stream>>>(xn, wqkv1b, Qb);
  attn_fwd<<<512, 256, 0, stream>>>(Qb, Kb, Vtb, xn);
  gemm_out<<<256, 512, 65536, stream>>>(xn, wo1b, bo1, x, x1, 1024, 1024);

  // ---- attention block 2 ----
  ln_kernel<<<4096, 256, 0, stream>>>(x1, ln2g, ln2b, xn);
  gemm_qkv<<<192, 512, 131072, stream>>>(xn, wqkv2b, Qb);
  attn_fwd<<<512, 256, 0, stream>>>(Qb, Kb, Vtb, xn);
  gemm_out<<<256, 512, 65536, stream>>>(xn, wo2b, bo2, x1, x2, 1024, 1024);

  // ---- GEGLU FF ----
  ln_kernel<<<4096, 256, 0, stream>>>(x2, ln3g, ln3b, xn);
  gemm_ff1<<<512, 512, 131072, stream>>>(xn, wff1p, bff1, hact);
  gemm_out<<<256, 512, 65536, stream>>>(hact, wff2b, bff2, x2, (float*)d_out, 1024, 4096);
}

// Round 14
// 347.334 us; speedup vs baseline: 1.2157x; 1.0361x over previous
//
#include <hip/hip_runtime.h>
#include <hip/hip_bf16.h>

using bf16x8 = __attribute__((ext_vector_type(8))) short;
using f32x4  = __attribute__((ext_vector_type(4))) float;
typedef unsigned int u32;
typedef unsigned short u16;
using u32x4 = __attribute__((ext_vector_type(4))) u32;

__device__ __forceinline__ u16 f2b(float f) {
  union { float f; u32 u; } v; v.f = f;
  return (u16)((v.u + 0x7FFFu + ((v.u >> 16) & 1u)) >> 16);
}

__device__ __forceinline__ u32 cvtpk(float lo, float hi) {
  u32 r;
  asm("v_cvt_pk_bf16_f32 %0, %1, %2" : "=v"(r) : "v"(lo), "v"(hi));
  return r;
}

__device__ __forceinline__ float exp2_raw(float x) {
  float r;
  asm("v_exp_f32 %0, %1" : "=v"(r) : "v"(x));
  return r;
}

__device__ __forceinline__ void gload16(const void* g, void* l) {
  __builtin_amdgcn_global_load_lds((const __attribute__((address_space(1))) u32*)g,
                                   (__attribute__((address_space(3))) u32*)l, 16, 0, 0);
}

// gelu via tanh approx: x * u/(u+1), u = 2^(2*0.79788456*log2e*(x+0.044715x^3))
__device__ __forceinline__ float gelu_fast(float x) {
  const float x2 = x * x;
  const float t = x * fmaf(0.044715f, x2, 1.f);
  const float u = exp2f(2.3022080f * t);
  return x * u * __builtin_amdgcn_rcpf(u + 1.f);
}

// ---------------------------------------------------------------------------
// Fused weight cast fp32 -> bf16 (QKV packed; FF1 a/gate interleaved per 16)
// ---------------------------------------------------------------------------
__global__ __launch_bounds__(256) void castall(
    const float* __restrict__ wq1, const float* __restrict__ wk1,
    const float* __restrict__ wv1, const float* __restrict__ wo1,
    const float* __restrict__ wq2, const float* __restrict__ wk2,
    const float* __restrict__ wv2, const float* __restrict__ wo2,
    const float* __restrict__ wff1, const float* __restrict__ wff2,
    u16* __restrict__ qkv1, u16* __restrict__ o1,
    u16* __restrict__ qkv2, u16* __restrict__ o2,
    u16* __restrict__ ff1p, u16* __restrict__ ff2) {
  const long e = ((long)blockIdx.x * 256 + threadIdx.x) * 4;
  constexpr long M1 = 1l << 20;
  const float* s; u16* d;
  if (e < 3 * M1) {
    s = (e < M1 ? wq1 + e : (e < 2 * M1 ? wk1 + (e - M1) : wv1 + (e - 2 * M1)));
    d = qkv1 + e;
  } else if (e < 4 * M1) {
    s = wo1 + (e - 3 * M1); d = o1 + (e - 3 * M1);
  } else if (e < 7 * M1) {
    long r = e - 4 * M1;
    s = (r < M1 ? wq2 + r : (r < 2 * M1 ? wk2 + (r - M1) : wv2 + (r - 2 * M1)));
    d = qkv2 + r;
  } else if (e < 8 * M1) {
    s = wo2 + (e - 7 * M1); d = o2 + (e - 7 * M1);
  } else if (e < 16 * M1) {
    long r = e - 8 * M1;
    long p = r >> 10, col = r & 1023;
    long g = p >> 5, rr = p & 31;
    long lr = (rr < 16) ? (g << 4) + rr : 4096 + (g << 4) + (rr - 16);
    s = wff1 + (lr << 10) + col; d = ff1p + r;
  } else {
    long r = e - 16 * M1;
    s = wff2 + r; d = ff2 + r;
  }
  float4 v = *(const float4*)s;
  ushort4 o;
  o.x = f2b(v.x); o.y = f2b(v.y); o.z = f2b(v.z); o.w = f2b(v.w);
  *(ushort4*)d = o;
}

// ---------------------------------------------------------------------------
// LayerNorm: one block per row of 1024, fp32 in -> bf16 out
// ---------------------------------------------------------------------------
__global__ __launch_bounds__(256) void ln_kernel(const float* __restrict__ x,
                                                 const float* __restrict__ g,
                                                 const float* __restrict__ b,
                                                 u16* __restrict__ y) {
  const int row = blockIdx.x;
  const int t = threadIdx.x;
  const float* xr = x + (size_t)row * 1024;
  float4 v = ((const float4*)xr)[t];
  float s  = v.x + v.y + v.z + v.w;
  float s2 = v.x * v.x + v.y * v.y + v.z * v.z + v.w * v.w;
  #pragma unroll
  for (int m = 1; m < 64; m <<= 1) {
    s  += __shfl_xor(s, m);
    s2 += __shfl_xor(s2, m);
  }
  __shared__ float red[8];
  if ((t & 63) == 0) { red[(t >> 6) * 2] = s; red[(t >> 6) * 2 + 1] = s2; }
  __syncthreads();
  s  = red[0] + red[2] + red[4] + red[6];
  s2 = red[1] + red[3] + red[5] + red[7];
  const float mu = s * (1.f / 1024.f);
  const float var = s2 * (1.f / 1024.f) - mu * mu;
  const float rs = rsqrtf(var + 1e-5f);
  float4 gv = ((const float4*)g)[t];
  float4 bv = ((const float4*)b)[t];
  ushort4 o;
  o.x = f2b((v.x - mu) * rs * gv.x + bv.x);
  o.y = f2b((v.y - mu) * rs * gv.y + bv.y);
  o.z = f2b((v.z - mu) * rs * gv.z + bv.z);
  o.w = f2b((v.w - mu) * rs * gv.w + bv.w);
  ((ushort4*)(y + (size_t)row * 1024))[t] = o;
}

// ---------------------------------------------------------------------------
// gemm_out: C[M,N] = A[M,K] @ Bw[N,K]^T, fp32 out = acc + bias + resid.
// 128x128 tile, 8 waves, BK=64, dbuf, XOR swizzle, counted vmcnt, setprio.
// ---------------------------------------------------------------------------
__global__ __launch_bounds__(512, 4) void gemm_out(
    const u16* __restrict__ A, const u16* __restrict__ Bw,
    const float* __restrict__ bias, const float* __restrict__ resid,
    float* __restrict__ out, int N, int K) {
  extern __shared__ u16 lds[];
  const int tid = threadIdx.x;
  const int l = tid & 63, wid = tid >> 6;
  const int li = l & 15, lg = l >> 4;
  const int wr = wid >> 2, wc = wid & 3;
  const int nx = N >> 7;
  const int cpx = gridDim.x >> 3;
  const int v = (blockIdx.x & 7) * cpx + (blockIdx.x >> 3);
  const int by = v / nx, bx = v - by * nx;
  const int m0 = by << 7, n0 = bx << 7;

  const int sr = tid >> 3;
  const int sc = ((tid & 7) ^ (sr & 7)) << 3;
  const int dc = (tid & 7) << 3;
  const int sc0 = (lg * 8) ^ ((li & 7) << 3);
  const int sc1 = sc0 ^ 32;

  f32x4 acc[4][2] = {};

  auto stageA = [&](int kb, int t2) {
    #pragma unroll
    for (int s = 0; s < 2; ++s)
      gload16(A + (size_t)(m0 + s * 64 + sr) * K + t2 * 64 + sc,
              lds + kb * 8192 + (s * 64 + sr) * 64 + dc);
  };
  auto stageB = [&](int kb, int t2) {
    #pragma unroll
    for (int s = 0; s < 2; ++s)
      gload16(Bw + (size_t)(n0 + s * 64 + sr) * K + t2 * 64 + sc,
              lds + 16384 + kb * 8192 + (s * 64 + sr) * 64 + dc);
  };

  const int NT = K >> 6;
  stageA(0, 0); stageB(0, 0);
  __builtin_amdgcn_sched_barrier(0);
  stageA(1, 1); stageB(1, 1);
  __builtin_amdgcn_sched_barrier(0);
  asm volatile("s_waitcnt vmcnt(4)" ::: "memory");
  __builtin_amdgcn_s_barrier();
  __builtin_amdgcn_sched_barrier(0);

  for (int t = 0; t < NT; ++t) {
    const int kb = t & 1;
    const u16* Ab = lds + kb * 8192 + (wr * 64 + li) * 64;
    const u16* Bb = lds + 16384 + kb * 8192 + (wc * 32 + li) * 64;
    bf16x8 a[4], b[2];

    #pragma unroll
    for (int mi = 0; mi < 4; ++mi) a[mi] = *(const bf16x8*)(Ab + mi * 1024 + sc0);
    #pragma unroll
    for (int n = 0; n < 2; ++n)  b[n]  = *(const bf16x8*)(Bb + n * 1024 + sc0);
    __builtin_amdgcn_s_barrier();
    __builtin_amdgcn_s_setprio(1);
    #pragma unroll
    for (int mi = 0; mi < 4; ++mi)
      #pragma unroll
      for (int n = 0; n < 2; ++n)
        acc[mi][n] = __builtin_amdgcn_mfma_f32_16x16x32_bf16(a[mi], b[n], acc[mi][n], 0, 0, 0);
    __builtin_amdgcn_s_setprio(0);
    __builtin_amdgcn_s_barrier();

    #pragma unroll
    for (int mi = 0; mi < 4; ++mi) a[mi] = *(const bf16x8*)(Ab + mi * 1024 + sc1);
    #pragma unroll
    for (int n = 0; n < 2; ++n)  b[n]  = *(const bf16x8*)(Bb + n * 1024 + sc1);
    __builtin_amdgcn_s_barrier();
    __builtin_amdgcn_s_setprio(1);
    #pragma unroll
    for (int mi = 0; mi < 4; ++mi)
      #pragma unroll
      for (int n = 0; n < 2; ++n)
        acc[mi][n] = __builtin_amdgcn_mfma_f32_16x16x32_bf16(a[mi], b[n], acc[mi][n], 0, 0, 0);
    __builtin_amdgcn_s_setprio(0);
    if (t + 2 < NT) {
      stageA(kb, t + 2); stageB(kb, t + 2);
      asm volatile("s_waitcnt vmcnt(4)" ::: "memory");
    } else if (t + 2 == NT) {
      asm volatile("s_waitcnt vmcnt(0)" ::: "memory");
    }
    __builtin_amdgcn_s_barrier();
    __builtin_amdgcn_sched_barrier(0);
  }

  #pragma unroll
  for (int mi = 0; mi < 4; ++mi) {
    const int m = m0 + wr * 64 + mi * 16 + lg * 4;
    #pragma unroll
    for (int n = 0; n < 2; ++n) {
      const int j = n0 + wc * 32 + n * 16 + li;
      const float bj = bias[j];
      #pragma unroll
      for (int rb = 0; rb < 4; ++rb)
        out[(size_t)(m + rb) * N + j] =
            acc[mi][n][rb] + bj + resid[(size_t)(m + rb) * N + j];
    }
  }
}

// ===========================================================================
// 256x256 4-phase K-loop, ONE barrier per phase (4/tile).
// ===========================================================================
#define KLOOP_PROLOGUE()                                                      \
  stageA(0, 0); stageB(0, 0); stageA(1, 0); stageB(1, 0);                     \
  __builtin_amdgcn_sched_barrier(0);                                          \
  stageA(0, 1); stageB(0, 1);                                                 \
  __builtin_amdgcn_sched_barrier(0);                                          \
  asm volatile("s_waitcnt vmcnt(4)" ::: "memory");                            \
  __builtin_amdgcn_s_barrier();                                               \
  __builtin_amdgcn_sched_barrier(0);

#define KLOOP_BODY(NT)                                                        \
  bf16x8 b0[4], b1[4];                                                        \
  for (int t = 0; t < NT; ++t) {                                              \
    const int kb = t & 1;                                                     \
    const u16* Abase0 = lds + (kb * 2 + 0) * 8192 + rowA0;                    \
    const u16* Abase1 = lds + (kb * 2 + 1) * 8192 + rowA0;                    \
    const u16* Bbase  = lds + (kb * 2 + bhn) * 8192 + rowB0;                  \
    bf16x8 a[4];                                                              \
    /* phase 1: (qm0, k0) */                                                  \
    _Pragma("unroll")                                                         \
    for (int j = 0; j < 4; ++j) a[j]  = *(const bf16x8*)(Abase0 + j * 1024 + sc0); \
    _Pragma("unroll")                                                         \
    for (int n = 0; n < 4; ++n) b0[n] = *(const bf16x8*)(Bbase + n * 1024 + sc0); \
    if (t + 1 < NT) stageA(1, t + 1);                                         \
    __builtin_amdgcn_s_setprio(1);                                            \
    _Pragma("unroll")                                                         \
    for (int j = 0; j < 4; ++j)                                               \
      _Pragma("unroll")                                                       \
      for (int n = 0; n < 4; ++n)                                             \
        acc[j][n] = __builtin_amdgcn_mfma_f32_16x16x32_bf16(a[j], b0[n], acc[j][n], 0, 0, 0); \
    __builtin_amdgcn_s_setprio(0);                                            \
    __builtin_amdgcn_s_barrier();                                             \
    /* phase 2: (qm0, k1) */                                                  \
    _Pragma("unroll")                                                         \
    for (int j = 0; j < 4; ++j) a[j]  = *(const bf16x8*)(Abase0 + j * 1024 + sc1); \
    _Pragma("unroll")                                                         \
    for (int n = 0; n < 4; ++n) b1[n] = *(const bf16x8*)(Bbase + n * 1024 + sc1); \
    if (t + 1 < NT) stageB(1, t + 1);                                         \
    __builtin_amdgcn_s_setprio(1);                                            \
    _Pragma("unroll")                                                         \
    for (int j = 0; j < 4; ++j)                                               \
      _Pragma("unroll")                                                       \
      for (int n = 0; n < 4; ++n)                                             \
        acc[j][n] = __builtin_amdgcn_mfma_f32_16x16x32_bf16(a[j], b1[n], acc[j][n], 0, 0, 0); \
    __builtin_amdgcn_s_setprio(0);                                            \
    __builtin_amdgcn_s_barrier();                                             \
    /* phase 3: (qm1, k0) */                                                  \
    _Pragma("unroll")                                                         \
    for (int j = 0; j < 4; ++j) a[j] = *(const bf16x8*)(Abase1 + j * 1024 + sc0); \
    if (t + 2 < NT) stageA(0, t + 2);                                         \
    __builtin_amdgcn_s_setprio(1);                                            \
    _Pragma("unroll")                                                         \
    for (int j = 0; j < 4; ++j)                                               \
      _Pragma("unroll")                                                       \
      for (int n = 0; n < 4; ++n)                                             \
        acc[4 + j][n] = __builtin_amdgcn_mfma_f32_16x16x32_bf16(a[j], b0[n], acc[4 + j][n], 0, 0, 0); \
    __builtin_amdgcn_s_setprio(0);                                            \
    __builtin_amdgcn_s_barrier();                                             \
    /* phase 4: (qm1, k1) */                                                  \
    _Pragma("unroll")                                                         \
    for (int j = 0; j < 4; ++j) a[j] = *(const bf16x8*)(Abase1 + j * 1024 + sc1); \
    if (t + 2 < NT) stageB(0, t + 2);                                         \
    __builtin_amdgcn_s_setprio(1);                                            \
    _Pragma("unroll")                                                         \
    for (int j = 0; j < 4; ++j)                                               \
      _Pragma("unroll")                                                       \
      for (int n = 0; n < 4; ++n)                                             \
        acc[4 + j][n] = __builtin_amdgcn_mfma_f32_16x16x32_bf16(a[j], b1[n], acc[4 + j][n], 0, 0, 0); \
    __builtin_amdgcn_s_setprio(0);                                            \
    if (t < NT - 2)       asm volatile("s_waitcnt vmcnt(4)" ::: "memory");    \
    else if (t == NT - 2) asm volatile("s_waitcnt vmcnt(0)" ::: "memory");    \
    __builtin_amdgcn_s_barrier();                                             \
  }

// ---------------------------------------------------------------------------
// FF1: 256x256 packed-GEGLU GEMM. XCD decode: 8x8 2D chunk per XCD.
// ---------------------------------------------------------------------------
__global__ __launch_bounds__(512, 2) void gemm_ff1(
    const u16* __restrict__ A, const u16* __restrict__ Wp,
    const float* __restrict__ bias, u16* __restrict__ out) {
  extern __shared__ u16 lds[];
  const int tid = threadIdx.x;
  const int l = tid & 63, wid = tid >> 6;
  const int li = l & 15, lg = l >> 4;
  const int wr = wid >> 2, wc = wid & 3;
  const int xcd = blockIdx.x & 7, r = blockIdx.x >> 3;   // r in [0,64)
  const int bx = (xcd & 3) * 8 + (r >> 3);               // [0,32)
  const int by = (xcd >> 2) * 8 + (r & 7);               // [0,16)

  const int lr8 = l >> 3;
  const int scb = ((l & 7) ^ lr8) << 3;
  const int sc0 = (lg * 8) ^ ((li & 7) << 3);
  const int sc1 = sc0 ^ 32;

  const int rowA0 = (wr * 64 + li) * 64;
  const int rowB0 = 32768 + ((wc & 1) * 64 + li) * 64;
  const int bhn = wc >> 1;

  f32x4 acc[8][4] = {};

  auto stageA = [&](int h, int t2) {
    const int kb2 = t2 & 1;
    #pragma unroll
    for (int s = 0; s < 2; ++s) {
      const u16* g = A + (size_t)(by * 256 + s * 128 + h * 64 + wid * 8 + lr8) * 1024
                       + t2 * 64 + scb;
      u16* d = lds + (kb2 * 2 + h) * 8192 + s * 4096 + wid * 512;
      gload16(g, d);
    }
  };
  auto stageB = [&](int h, int t2) {
    const int kb2 = t2 & 1;
    #pragma unroll
    for (int s = 0; s < 2; ++s) {
      const u16* g = Wp + (size_t)(bx * 256 + h * 128 + s * 64 + wid * 8 + lr8) * 1024
                        + t2 * 64 + scb;
      u16* d = lds + 32768 + (kb2 * 2 + h) * 8192 + s * 4096 + wid * 512;
      gload16(g, d);
    }
  };

  KLOOP_PROLOGUE()
  KLOOP_BODY(16)

  #pragma unroll
  for (int nj = 0; nj < 2; ++nj) {
    const int c = bx * 128 + wc * 32 + nj * 16 + li;
    const float ba = bias[c];
    const float bg = bias[4096 + c];
    #pragma unroll
    for (int mi = 0; mi < 8; ++mi) {
      #pragma unroll
      for (int rb = 0; rb < 4; ++rb) {
        const float av = acc[mi][2 * nj][rb] + ba;
        const float gv = acc[mi][2 * nj + 1][rb] + bg;
        out[(size_t)(by * 256 + wr * 128 + mi * 16 + lg * 4 + rb) * 4096 + c]
            = f2b(av * gelu_fast(gv));
      }
    }
  }
}

// ---------------------------------------------------------------------------
// QKV: 256x256 4-phase GEMM, N=3072. XCD decode: 4by x 6bx chunk per XCD.
// V epilogue bakes the 16x16 PV slot permutation:
//   slot = (k&3) | ((k&12)<<1) | ((k&16)>>2) | (k&32), col = slot ^ ((d&7)<<3)
// ---------------------------------------------------------------------------
__global__ __launch_bounds__(512, 2) void gemm_qkv(
    const u16* __restrict__ A, const u16* __restrict__ Wp,
    u16* __restrict__ outp) {
  extern __shared__ u16 lds[];
  const int tid = threadIdx.x;
  const int l = tid & 63, wid = tid >> 6;
  const int li = l & 15, lg = l >> 4;
  const int wr = wid >> 2, wc = wid & 3;
  const int xcd = blockIdx.x & 7, r = blockIdx.x >> 3;   // r in [0,24)
  const int by = (xcd >> 1) * 4 + r / 6;                 // [0,16)
  const int bx = (xcd & 1) * 6 + r % 6;                  // [0,12)

  const int lr8 = l >> 3;
  const int scb = ((l & 7) ^ lr8) << 3;
  const int sc0 = (lg * 8) ^ ((li & 7) << 3);
  const int sc1 = sc0 ^ 32;

  const int rowA0 = (wr * 64 + li) * 64;
  const int rowB0 = 32768 + ((wc & 1) * 64 + li) * 64;
  const int bhn = wc >> 1;

  f32x4 acc[8][4] = {};

  auto stageA = [&](int h, int t2) {
    const int kb2 = t2 & 1;
    #pragma unroll
    for (int s = 0; s < 2; ++s) {
      const u16* g = A + (size_t)(by * 256 + s * 128 + h * 64 + wid * 8 + lr8) * 1024
                       + t2 * 64 + scb;
      u16* d = lds + (kb2 * 2 + h) * 8192 + s * 4096 + wid * 512;
      gload16(g, d);
    }
  };
  auto stageB = [&](int h, int t2) {
    const int kb2 = t2 & 1;
    #pragma unroll
    for (int s = 0; s < 2; ++s) {
      const u16* g = Wp + (size_t)(bx * 256 + h * 128 + s * 64 + wid * 8 + lr8) * 1024
                        + t2 * 64 + scb;
      u16* d = lds + 32768 + (kb2 * 2 + h) * 8192 + s * 4096 + wid * 512;
      gload16(g, d);
    }
  };

  KLOOP_PROLOGUE()
  KLOOP_BODY(16)

  #pragma unroll
  for (int mi = 0; mi < 8; ++mi) {
    const int mbase = by * 256 + wr * 128 + mi * 16 + lg * 4;
    #pragma unroll
    for (int ni = 0; ni < 4; ++ni) {
      const int j = bx * 256 + wc * 64 + ni * 16 + li;
      f32x4 a = acc[mi][ni];
      const int sec = j >> 10, jj = j & 1023;
      const int h = jj >> 6, dd = jj & 63;
      u16* base = outp + (size_t)sec * 4194304;
      if (sec == 0) {
        #pragma unroll
        for (int rb = 0; rb < 4; ++rb) {
          const int m = mbase + rb;
          const int bb = m >> 11, n = m & 2047;
          base[(((size_t)bb * 16 + h) * 2048 + n) * 64 + dd] =
              f2b(a[rb] * 0.18033688011112042f);
        }
      } else if (sec == 1) {
        #pragma unroll
        for (int rb = 0; rb < 4; ++rb) {
          const int m = mbase + rb;
          const int bb = m >> 11, n = m & 2047;
          base[(((size_t)bb * 16 + h) * 2048 + n) * 64 + (dd ^ ((n & 7) << 3))] =
              f2b(a[rb]);
        }
      } else {
        const int bb = mbase >> 11, n = mbase & 2047;
        const int ng = n & ~63, nl = n & 63;
        const int slot = (nl & 3) | ((nl & 12) << 1) | ((nl & 16) >> 2) | (nl & 32);
        const int col = ng | (slot ^ ((dd & 7) << 3));
        ushort4 pk;
        pk.x = f2b(a[0]); pk.y = f2b(a[1]); pk.z = f2b(a[2]); pk.w = f2b(a[3]);
        *(ushort4*)&base[(((size_t)bb * 16 + h) * 64 + dd) * 2048 + col] = pk;
      }
    }
  }
}

// ---------------------------------------------------------------------------
// Flash attention, 16x16x32 MFMA, 16 q-rows/wave -> 1024 blocks, 4 waves/SIMD.
// Swapped QK^T (lane q = l&15, holds 16 keys), static-shift softmax,
// V slot-permuted so P feeds PV with zero cross-lane exchange.
// 2-buffer LDS, vmcnt(0)/tile (TLP hides the drain). lacc via ones-MFMA.
// ---------------------------------------------------------------------------
__global__ __launch_bounds__(256, 4) void attn_fwd(
    const u16* __restrict__ Q, const u16* __restrict__ K,
    const u16* __restrict__ Vt, u16* __restrict__ Out) {
  __shared__ u16 smem[2][8192];
  const int tid = threadIdx.x;
  const int l = tid & 63, w = tid >> 6;
  const int li = l & 15, hi4 = l >> 4, l7 = l & 7;
  const int bh = blockIdx.x & 31, qt = blockIdx.x >> 5;   // qt 0..31
  const int b_ = bh >> 4, h = bh & 15;

  const u16* Qg = Q + ((size_t)bh * 2048 + qt * 64 + w * 16 + li) * 64;
  const u16* Kg = K + (size_t)bh * 2048 * 64;
  const u16* Vg = Vt + (size_t)bh * 64 * 2048;

  const bf16x8 qf0 = *(const bf16x8*)&Qg[hi4 * 8];
  const bf16x8 qf1 = *(const bf16x8*)&Qg[32 + hi4 * 8];

  const bf16x8 onesf = {(short)0x3F80, (short)0x3F80, (short)0x3F80, (short)0x3F80,
                        (short)0x3F80, (short)0x3F80, (short)0x3F80, (short)0x3F80};

  f32x4 o[4] = {};
  f32x4 lacc = {};

  auto stage = [&](int buf, int jt) {
    #pragma unroll
    for (int i = 0; i < 2; ++i)
      gload16(Kg + (size_t)jt * 4096 + i * 2048 + tid * 8,
              &smem[buf][i * 2048 + w * 512]);
    #pragma unroll
    for (int i = 0; i < 2; ++i)
      gload16(Vg + (size_t)(w * 8 + (l >> 3) + i * 32) * 2048 + jt * 64 + l7 * 8,
              &smem[buf][4096 + i * 2048 + w * 512]);
  };

  stage(0, 0);

  for (int jt = 0; jt < 32; ++jt) {
    const int cur = jt & 1;
    asm volatile("s_waitcnt vmcnt(0)" ::: "memory");
    __builtin_amdgcn_s_barrier();
    __builtin_amdgcn_sched_barrier(0);
    if (jt + 1 < 32) stage(cur ^ 1, jt + 1);

    const u16* Kl = &smem[cur][0];
    const u16* Vl = &smem[cur][4096];
    const int c0 = (hi4 * 8) ^ (l7 << 3);
    const int c1 = (32 + hi4 * 8) ^ (l7 << 3);

    // QK^T: st[g][r] = S[key = g*16 + hi4*4 + r][q = li]
    f32x4 st[4] = {};
    __builtin_amdgcn_s_setprio(1);
    #pragma unroll
    for (int g = 0; g < 4; ++g) {
      const bf16x8 kf0 = *(const bf16x8*)&Kl[(g * 16 + li) * 64 + c0];
      const bf16x8 kf1 = *(const bf16x8*)&Kl[(g * 16 + li) * 64 + c1];
      st[g] = __builtin_amdgcn_mfma_f32_16x16x32_bf16(kf0, qf0, st[g], 0, 0, 0);
      st[g] = __builtin_amdgcn_mfma_f32_16x16x32_bf16(kf1, qf1, st[g], 0, 0, 0);
    }
    __builtin_amdgcn_s_setprio(0);

    // P = 2^(st - 8): static shift (logits bounded), no max tracking
    float p[16];
    #pragma unroll
    for (int g = 0; g < 4; ++g)
      #pragma unroll
      for (int r = 0; r < 4; ++r)
        p[g * 4 + r] = exp2_raw(st[g][r] - 8.f);

    // pack: slot permutation makes pf0 = p[0..7], pf1 = p[8..15] directly
    u32x4 w0, w1;
    #pragma unroll
    for (int t2 = 0; t2 < 4; ++t2) {
      w0[t2] = cvtpk(p[t2 * 2], p[t2 * 2 + 1]);
      w1[t2] = cvtpk(p[8 + t2 * 2], p[8 + t2 * 2 + 1]);
    }
    union { u32x4 a; bf16x8 b; } cc0, cc1;
    cc0.a = w0; cc1.a = w1;
    const bf16x8 pf0 = cc0.b, pf1 = cc1.b;

    __builtin_amdgcn_s_setprio(1);
    #pragma unroll
    for (int dc = 0; dc < 4; ++dc) {
      const bf16x8 vf0 = *(const bf16x8*)&Vl[(dc * 16 + li) * 64 + c0];
      const bf16x8 vf1 = *(const bf16x8*)&Vl[(dc * 16 + li) * 64 + c1];
      o[dc] = __builtin_amdgcn_mfma_f32_16x16x32_bf16(vf0, pf0, o[dc], 0, 0, 0);
      o[dc] = __builtin_amdgcn_mfma_f32_16x16x32_bf16(vf1, pf1, o[dc], 0, 0, 0);
    }
    lacc = __builtin_amdgcn_mfma_f32_16x16x32_bf16(onesf, pf0, lacc, 0, 0, 0);
    lacc = __builtin_amdgcn_mfma_f32_16x16x32_bf16(onesf, pf1, lacc, 0, 0, 0);
    __builtin_amdgcn_s_setprio(0);
  }

  const float inv = 1.f / lacc[0];
  const int q = qt * 64 + w * 16 + li;
  u16* Ob = Out + ((size_t)b_ * 2048 + q) * 1024 + h * 64;
  #pragma unroll
  for (int dc = 0; dc < 4; ++dc) {
    ushort4 pk;
    pk.x = f2b(o[dc][0] * inv); pk.y = f2b(o[dc][1] * inv);
    pk.z = f2b(o[dc][2] * inv); pk.w = f2b(o[dc][3] * inv);
    *(ushort4*)&Ob[dc * 16 + hi4 * 4] = pk;
  }
}

// ---------------------------------------------------------------------------
// Host launch
// ---------------------------------------------------------------------------
extern "C" void kernel_launch(void* const* d_in, const int* in_sizes, int n_in,
                              void* d_out, int out_size, void* d_ws, size_t ws_size,
                              hipStream_t stream) {
  const float* x    = (const float*)d_in[0];
  const float* ln1g = (const float*)d_in[1];
  const float* ln1b = (const float*)d_in[2];
  const float* wq1  = (const float*)d_in[3];
  const float* wk1  = (const float*)d_in[4];
  const float* wv1  = (const float*)d_in[5];
  const float* wo1  = (const float*)d_in[6];
  const float* bo1  = (const float*)d_in[7];
  const float* ln2g = (const float*)d_in[8];
  const float* ln2b = (const float*)d_in[9];
  const float* wq2  = (const float*)d_in[10];
  const float* wk2  = (const float*)d_in[11];
  const float* wv2  = (const float*)d_in[12];
  const float* wo2  = (const float*)d_in[13];
  const float* bo2  = (const float*)d_in[14];
  const float* ln3g = (const float*)d_in[15];
  const float* ln3b = (const float*)d_in[16];
  const float* wff1 = (const float*)d_in[17];
  const float* bff1 = (const float*)d_in[18];
  const float* wff2 = (const float*)d_in[19];
  const float* bff2 = (const float*)d_in[20];

  char* ws = (char*)d_ws;
  const size_t MB = 1024 * 1024;
  u16* wqkv1b = (u16*)(ws + 0 * MB);
  u16* wo1b   = (u16*)(ws + 6 * MB);
  u16* wqkv2b = (u16*)(ws + 8 * MB);
  u16* wo2b   = (u16*)(ws + 14 * MB);
  u16* wff1p  = (u16*)(ws + 16 * MB);
  u16* wff2b  = (u16*)(ws + 32 * MB);
  u16* xn     = (u16*)(ws + 40 * MB);
  u16* Qb     = (u16*)(ws + 48 * MB);
  float* x1   = (float*)(ws + 72 * MB);
  float* x2   = (float*)(ws + 88 * MB);
  u16* hact   = (u16*)(ws + 48 * MB);
  u16* Kb  = Qb + 4194304;
  u16* Vtb = Qb + 8388608;

  hipFuncSetAttribute((const void*)gemm_ff1,
                      hipFuncAttributeMaxDynamicSharedMemorySize, 131072);
  hipFuncSetAttribute((const void*)gemm_qkv,
                      hipFuncAttributeMaxDynamicSharedMemorySize, 131072);
  hipFuncSetAttribute((const void*)gemm_out,
                      hipFuncAttributeMaxDynamicSharedMemorySize, 65536);

  castall<<<20480, 256, 0, stream>>>(wq1, wk1, wv1, wo1, wq2, wk2, wv2, wo2,
                                     wff1, wff2,
                                     wqkv1b, wo1b, wqkv2b, wo2b, wff1p, wff2b);

  // ---- attention block 1 ----
  ln_kernel<<<4096, 256, 0, stream>>>(x, ln1g, ln1b, xn);
  gemm_qkv<<<192, 512, 131072, stream>>>(xn, wqkv1b, Qb);
  attn_fwd<<<1024, 256, 0, stream>>>(Qb, Kb, Vtb, xn);
  gemm_out<<<256, 512, 65536, stream>>>(xn, wo1b, bo1, x, x1, 1024, 1024);

  // ---- attention block 2 ----
  ln_kernel<<<4096, 256, 0, stream>>>(x1, ln2g, ln2b, xn);
  gemm_qkv<<<192, 512, 131072, stream>>>(xn, wqkv2b, Qb);
  attn_fwd<<<1024, 256, 0, stream>>>(Qb, Kb, Vtb, xn);
  gemm_out<<<256, 512, 65536, stream>>>(xn, wo2b, bo2, x1, x2, 1024, 1024);

  // ---- GEGLU FF ----
  ln_kernel<<<4096, 256, 0, stream>>>(x2, ln3g, ln3b, xn);
  gemm_ff1<<<512, 512, 131072, stream>>>(xn, wff1p, bff1, hact);
  gemm_out<<<256, 512, 65536, stream>>>(hact, wff2b, bff2, x2, (float*)d_out, 1024, 4096);
}